// Round 9
// baseline (500.971 us; speedup 1.0000x reference)
//
#include <hip/hip_runtime.h>
#include <math.h>
#include <stdint.h>

#define BATCH 4096
#define FEAT  1024
#define EDIM  16
#define NDOM  8
#define TDIM  1040
#define KP1   1088
#define NLAYER 3
#define EPSV  1e-5f
#define GRID  512
#define MAGIC 0x13371337u

typedef __attribute__((ext_vector_type(8))) short bf16x8;
typedef __attribute__((ext_vector_type(4))) float f32x4;

__device__ __forceinline__ unsigned short f2bf(float f) {
    union { float f; unsigned int u; } v; v.f = f;
    unsigned int u = v.u;
    return (unsigned short)((u + 0x7fffu + ((u >> 16) & 1u)) >> 16);
}
__device__ __forceinline__ float bf2f(unsigned short u) {
    union { unsigned int u; float f; } v; v.u = ((unsigned int)u) << 16; return v.f;
}
__device__ __forceinline__ void gload_lds16(const void* g, void* l) {
    __builtin_amdgcn_global_load_lds(
        (const __attribute__((address_space(1))) void*)(g),
        (__attribute__((address_space(3))) void*)(l), 16, 0, 0);
}

#define T_W1 136
#define T_W2 32
#define T_W3 8
#define NCONV (T_W1*9 + T_W2*9 + T_W3*9)   // 1584
#define FRONT_U (1 + NCONV + BATCH)         // 5681
#define L1_TILES (4 * (32 + NDOM * 32))     // 1152
#define L2_TILES (2 * (32 + NDOM * 32))     // 576
#define D_TILES  (NDOM * 128)               // 1024

struct P {
    const int* dom; int* perm; int* starts; unsigned* bar;
    const float *cW1,*dW1,*cW2,*dW2,*cW3,*dW3;
    unsigned short *Wc1b,*Wd1b,*Wc2b,*Wd2b,*Wc3b,*Wd3b;
    const float *x,*pnw,*pnb,*demb,*crw,*crb,*aW1,*ab1,*aW2,*ab2;
    unsigned short *XCb,*H1c,*H1d,*H2c,*H2d;
    const float *cb1,*db1,*cb2,*db2,*cb3,*db3,*fW1,*fb1,*fW2,*fb2;
    float* auxg; float* out;
};

// device-scope arrival barrier; bounded spin (timeout -> proceed, absmax will flag)
__device__ __forceinline__ void gbar(unsigned* bar, int idx) {
    __syncthreads();
    if (threadIdx.x == 0) {
        __threadfence();
        atomicAdd(&bar[idx], 1u);
        int spins = 0;
        while (atomicAdd(&bar[idx], 0u) < (unsigned)GRID && spins < 2000000) {
            __builtin_amdgcn_s_sleep(8);
            spins++;
        }
    }
    __syncthreads();
    __threadfence();
}

// ---------------- gemm tile: 128x128, BK=64, global_load_lds ----------------
__device__ __forceinline__ void gemm_tile(
    const unsigned short* __restrict__ A, const unsigned short* __restrict__ W,
    const float* __restrict__ bias, unsigned short* __restrict__ C,
    const int* __restrict__ perm, int usePerm,
    int m0, int mEnd, int n0, int lda, int Kp, int N, int relu,
    short* As, short* Bs) {
    int tid = threadIdx.x;
    int w = tid >> 6, lane = tid & 63;
    int wm = w >> 1, wn = w & 1;
    int lr = lane & 15, q = lane >> 4;

    const unsigned short* pA[4]; const unsigned short* pB[4];
    short* dA[4]; short* dB[4];
    #pragma unroll
    for (int i = 0; i < 4; i++) {
        int seg = i * 4 + w;
        int ch = seg * 64 + lane;
        int loc = ch >> 3, c = ch & 7;
        int mm = m0 + loc; if (mm > mEnd - 1) mm = mEnd - 1;
        int row = usePerm ? perm[mm] : mm;
        pA[i] = A + (size_t)row * lda + ((c ^ (loc & 7)) << 3);
        dA[i] = As + seg * 512;
        pB[i] = W + (size_t)(n0 + loc) * Kp + ((c ^ (loc & 7)) << 3);
        dB[i] = Bs + seg * 512;
    }

    f32x4 acc[4][4];
    #pragma unroll
    for (int i = 0; i < 4; i++)
        #pragma unroll
        for (int j = 0; j < 4; j++)
            acc[i][j] = (f32x4){0.f, 0.f, 0.f, 0.f};

    for (int k0 = 0; k0 < Kp; k0 += 64) {
        #pragma unroll
        for (int i = 0; i < 4; i++) gload_lds16(pA[i] + k0, dA[i]);
        #pragma unroll
        for (int i = 0; i < 4; i++) gload_lds16(pB[i] + k0, dB[i]);
        __syncthreads();

        #pragma unroll
        for (int half = 0; half < 2; half++) {
            int c = half * 4 + q;
            bf16x8 af[4], bf[4];
            #pragma unroll
            for (int i = 0; i < 4; i++) {
                int m = wm * 64 + i * 16 + lr;
                af[i] = *(const bf16x8*)(As + m * 64 + ((c ^ (m & 7)) << 3));
            }
            #pragma unroll
            for (int j = 0; j < 4; j++) {
                int n = wn * 64 + j * 16 + lr;
                bf[j] = *(const bf16x8*)(Bs + n * 64 + ((c ^ (n & 7)) << 3));
            }
            #pragma unroll
            for (int i = 0; i < 4; i++)
                #pragma unroll
                for (int j = 0; j < 4; j++)
                    acc[i][j] = __builtin_amdgcn_mfma_f32_16x16x32_bf16(
                        af[i], bf[j], acc[i][j], 0, 0, 0);
        }
        __syncthreads();
    }

    #pragma unroll
    for (int i = 0; i < 4; i++) {
        #pragma unroll
        for (int j = 0; j < 4; j++) {
            int col = n0 + wn * 64 + j * 16 + lr;
            float bvv = bias[col];
            int rowb = m0 + wm * 64 + i * 16 + q * 4;
            #pragma unroll
            for (int r = 0; r < 4; r++) {
                int row = rowb + r;
                if (row >= mEnd) continue;
                float val = acc[i][j][r] + bvv;
                if (relu) val = fmaxf(val, 0.f);
                C[(size_t)row * N + col] = f2bf(val);
            }
        }
    }
}

// ---------------- layer-3 unit: both chains + STAR tanh + final MLP + sigmoid ----------------
__device__ __forceinline__ void g3f_unit(const P& p, int d, int m0, int mEnd, char* smem) {
    short* As    = (short*)smem;
    short* Bs    = (short*)(smem + 4096);
    short* fused = (short*)(smem + 20480);

    int tid = threadIdx.x;
    int w = tid >> 6, lane = tid & 63;
    int wm = w >> 1, wn = w & 1;
    int lr = lane & 15, q = lane >> 4;
    const uint4 zero16 = make_uint4(0u, 0u, 0u, 0u);

    for (int chain = 0; chain < 2; chain++) {
        const unsigned short* A = chain ? p.H2d : p.H2c;
        const unsigned short* W = chain ? (p.Wd3b + (size_t)d * 128 * 256) : p.Wc3b;
        const float* bias = chain ? (p.db3 + d * 128) : p.cb3;
        f32x4 acc[4];
        #pragma unroll
        for (int j = 0; j < 4; j++) acc[j] = (f32x4){0.f, 0.f, 0.f, 0.f};

        for (int k0 = 0; k0 < 256; k0 += 64) {
            {
                int m = tid >> 3, c = tid & 7;
                int row = m0 + m;
                uint4 val = (row < mEnd)
                    ? *(const uint4*)(A + (size_t)row * 256 + k0 + c * 8) : zero16;
                *(uint4*)(As + m * 64 + ((c ^ (m & 7)) * 8)) = val;
            }
            #pragma unroll
            for (int i = 0; i < 4; i++) {
                int flat = tid + i * 256;
                int n = flat >> 3, c = flat & 7;
                uint4 val = *(const uint4*)(W + (size_t)n * 256 + k0 + c * 8);
                *(uint4*)(Bs + n * 64 + ((c ^ (n & 7)) * 8)) = val;
            }
            __syncthreads();
            #pragma unroll
            for (int g = 0; g < 2; g++) {
                int c = g * 4 + q;
                int m = wm * 16 + lr;
                bf16x8 af = *(const bf16x8*)(As + m * 64 + ((c ^ (m & 7)) * 8));
                #pragma unroll
                for (int j = 0; j < 4; j++) {
                    int n = wn * 64 + j * 16 + lr;
                    bf16x8 bf = *(const bf16x8*)(Bs + n * 64 + ((c ^ (n & 7)) * 8));
                    acc[j] = __builtin_amdgcn_mfma_f32_16x16x32_bf16(af, bf, acc[j], 0, 0, 0);
                }
            }
            __syncthreads();
        }
        #pragma unroll
        for (int j = 0; j < 4; j++) {
            int col = wn * 64 + j * 16 + lr;
            float bvv = bias[col];
            int cch = col >> 3;
            #pragma unroll
            for (int r = 0; r < 4; r++) {
                int row = wm * 16 + q * 4 + r;
                int pc = (cch & 8) | ((cch ^ (row & 7)) & 7);
                int idx = row * 128 + pc * 8 + (col & 7);
                if (chain == 0) {
                    fused[idx] = (short)f2bf(acc[j][r] + bvv);
                } else {
                    float cv = bf2f((unsigned short)fused[idx]);
                    fused[idx] = (short)f2bf(cv * tanhf(acc[j][r] + bvv));
                }
            }
        }
        __syncthreads();
    }

    short* Bsf = Bs;
    float* Ls  = (float*)As;
    for (int s2 = tid; s2 < 1024; s2 += 256) {
        int n = s2 >> 4, cch = s2 & 15;
        bf16x8 vv;
        #pragma unroll
        for (int kk = 0; kk < 8; kk++)
            vv[kk] = (short)f2bf(p.fW1[(cch * 8 + kk) * 64 + n]);
        int pc = (cch & 8) | ((cch ^ (n & 7)) & 7);
        *(bf16x8*)(Bsf + n * 128 + pc * 8) = vv;
    }
    __syncthreads();

    f32x4 acc2[2];
    #pragma unroll
    for (int j = 0; j < 2; j++) acc2[j] = (f32x4){0.f, 0.f, 0.f, 0.f};
    #pragma unroll
    for (int g = 0; g < 4; g++) {
        int c = g * 4 + q;
        int m = wm * 16 + lr;
        int pcm = (c & 8) | ((c ^ (m & 7)) & 7);
        bf16x8 af = *(const bf16x8*)(fused + m * 128 + pcm * 8);
        #pragma unroll
        for (int j = 0; j < 2; j++) {
            int n = wn * 32 + j * 16 + lr;
            int pcn = (c & 8) | ((c ^ (n & 7)) & 7);
            bf16x8 bf = *(const bf16x8*)(Bsf + n * 128 + pcn * 8);
            acc2[j] = __builtin_amdgcn_mfma_f32_16x16x32_bf16(af, bf, acc2[j], 0, 0, 0);
        }
    }

    float w2v[2], b1v[2];
    #pragma unroll
    for (int j = 0; j < 2; j++) {
        int col = wn * 32 + j * 16 + lr;
        w2v[j] = p.fW2[col];
        b1v[j] = p.fb1[col];
    }
    float rowv[4];
    #pragma unroll
    for (int r = 0; r < 4; r++) {
        float v = 0.f;
        #pragma unroll
        for (int j = 0; j < 2; j++)
            v += fmaxf(acc2[j][r] + b1v[j], 0.f) * w2v[j];
        v += __shfl_xor(v, 1);
        v += __shfl_xor(v, 2);
        v += __shfl_xor(v, 4);
        v += __shfl_xor(v, 8);
        rowv[r] = v;
    }
    if (wn == 0 && lr == 0) {
        #pragma unroll
        for (int r = 0; r < 4; r++)
            Ls[wm * 16 + q * 4 + r] = rowv[r];
    }
    __syncthreads();
    if (wn == 1 && lr == 0) {
        float b2 = p.fb2[0];
        #pragma unroll
        for (int r = 0; r < 4; r++) {
            int row = wm * 16 + q * 4 + r;
            int pp = m0 + row;
            if (pp < mEnd) {
                int orow = p.perm[pp];
                float logit = Ls[row] + rowv[r] + b2 + p.auxg[orow];
                p.out[orow] = 1.f / (1.f + expf(-logit));
            }
        }
    }
}

// ================= single plain-launch persistent kernel =================
__global__ __launch_bounds__(256, 2) void mega(P p) {
    __shared__ __align__(16) char smem[32768];
    __shared__ int cnt[NDOM];
    __shared__ int off[NDOM];
    __shared__ float redS[4];
    __shared__ float redQ[4];
    __shared__ float sMean, sRstd;

    int t = threadIdx.x;

    // ---- bootstrap barrier state (workspace is poisoned 0xAA each replay) ----
    if (blockIdx.x == 0) {
        if (t == 0) {
            p.bar[0] = 0u; p.bar[1] = 0u; p.bar[2] = 0u;
            __threadfence();
            atomicExch(&p.bar[3], MAGIC);
        }
    } else if (t == 0) {
        int spins = 0;
        while (atomicAdd(&p.bar[3], 0u) != MAGIC && spins < 2000000) {
            __builtin_amdgcn_s_sleep(8);
            spins++;
        }
    }
    __syncthreads();

    // ---------------- phase A: grouping + weight convert + prep ----------------
    for (int u = blockIdx.x; u < FRONT_U; u += GRID) {
        __syncthreads();
        if (u == 0) {
            if (t < NDOM) cnt[t] = 0;
            __syncthreads();
            for (int i = t; i < BATCH; i += 256) atomicAdd(&cnt[p.dom[i]], 1);
            __syncthreads();
            if (t == 0) {
                int s = 0;
                for (int d = 0; d < NDOM; d++) { off[d] = s; p.starts[d] = s; s += cnt[d]; }
                p.starts[NDOM] = s;
            }
            __syncthreads();
            for (int i = t; i < BATCH; i += 256) {
                int pos = atomicAdd(&off[p.dom[i]], 1);
                p.perm[pos] = i;
            }
        } else if (u <= NCONV) {
            float (*tile)[68] = (float(*)[68])smem;
            int bb = u - 1;
            const float* src; unsigned short* dst; int K, N, Kp, rr;
            if (bb < T_W1)            { src = p.cW1; dst = p.Wc1b; K = TDIM; N = 512; Kp = KP1; rr = bb; }
            else if (bb < T_W1*9)     { int r = bb - T_W1; int z = r / T_W1; rr = r % T_W1;
                                        src = p.dW1 + (size_t)z * TDIM * 512; dst = p.Wd1b + (size_t)z * 512 * KP1;
                                        K = TDIM; N = 512; Kp = KP1; }
            else if (bb < T_W1*9+T_W2)   { src = p.cW2; dst = p.Wc2b; K = 512; N = 256; Kp = 512; rr = bb - T_W1*9; }
            else if (bb < T_W1*9+T_W2*9) { int r = bb - (T_W1*9+T_W2); int z = r / T_W2; rr = r % T_W2;
                                        src = p.dW2 + (size_t)z * 512 * 256; dst = p.Wd2b + (size_t)z * 256 * 512;
                                        K = 512; N = 256; Kp = 512; }
            else if (bb < T_W1*9+T_W2*9+T_W3) { src = p.cW3; dst = p.Wc3b; K = 256; N = 128; Kp = 256; rr = bb - (T_W1*9+T_W2*9); }
            else                      { int r = bb - (T_W1*9+T_W2*9+T_W3); int z = r / T_W3; rr = r % T_W3;
                                        src = p.dW3 + (size_t)z * 256 * 128; dst = p.Wd3b + (size_t)z * 128 * 256;
                                        K = 256; N = 128; Kp = 256; }
            int kt = Kp >> 6;
            int kb = rr % kt, nb = rr / kt;
            int k0 = kb * 64, n0 = nb * 64;
            #pragma unroll
            for (int i = 0; i < 4; i++) {
                int flat = t + i * 256;
                int kr = flat >> 4, c4 = flat & 15;
                int k = k0 + kr;
                float4 v = make_float4(0.f, 0.f, 0.f, 0.f);
                if (k < K) v = *(const float4*)(src + (size_t)k * N + n0 + c4 * 4);
                *(float4*)(&tile[kr][c4 * 4]) = v;
            }
            __syncthreads();
            #pragma unroll
            for (int i = 0; i < 4; i++) {
                int flat = t + i * 256;
                int n = flat >> 4, kg = flat & 15;
                ushort4 sv;
                sv.x = f2bf(tile[kg * 4 + 0][n]);
                sv.y = f2bf(tile[kg * 4 + 1][n]);
                sv.z = f2bf(tile[kg * 4 + 2][n]);
                sv.w = f2bf(tile[kg * 4 + 3][n]);
                *(ushort4*)(dst + (size_t)(n0 + n) * Kp + k0 + kg * 4) = sv;
            }
        } else {
            float* x0s = (float*)smem;
            float* xcs = x0s + TDIM;
            int row = u - 1 - NCONV;
            int d = p.dom[row];

            float4 v = *(const float4*)(p.x + (size_t)row * FEAT + 4 * t);
            float s  = v.x + v.y + v.z + v.w;
            float ss = v.x*v.x + v.y*v.y + v.z*v.z + v.w*v.w;
            #pragma unroll
            for (int o = 32; o > 0; o >>= 1) {
                s  += __shfl_down(s,  o);
                ss += __shfl_down(ss, o);
            }
            if ((t & 63) == 0) { redS[t >> 6] = s; redQ[t >> 6] = ss; }
            __syncthreads();
            if (t == 0) {
                float S = redS[0] + redS[1] + redS[2] + redS[3];
                float Q = redQ[0] + redQ[1] + redQ[2] + redQ[3];
                float mean = S / (float)FEAT;
                float var  = Q / (float)FEAT - mean * mean;
                sMean = mean;
                sRstd = rsqrtf(var + EPSV);
            }
            __syncthreads();
            float mean = sMean, rstd = sRstd;

            float4 wv = *(const float4*)(p.pnw + (size_t)d * FEAT + 4 * t);
            float4 bv = *(const float4*)(p.pnb + (size_t)d * FEAT + 4 * t);
            {
                float n0 = (v.x - mean) * rstd * wv.x + bv.x;
                float n1 = (v.y - mean) * rstd * wv.y + bv.y;
                float n2 = (v.z - mean) * rstd * wv.z + bv.z;
                float n3 = (v.w - mean) * rstd * wv.w + bv.w;
                int j = 4 * t;
                x0s[j+0] = n0; x0s[j+1] = n1; x0s[j+2] = n2; x0s[j+3] = n3;
                xcs[j+0] = n0; xcs[j+1] = n1; xcs[j+2] = n2; xcs[j+3] = n3;
            }
            if (t < EDIM) {
                float e = p.demb[d * EDIM + t];
                x0s[FEAT + t] = e;
                xcs[FEAT + t] = e;
            }
            __syncthreads();

            for (int l = 0; l < NLAYER; l++) {
                float partial = 0.f;
                for (int j = t; j < TDIM; j += 256) partial += xcs[j] * p.crw[l * TDIM + j];
                #pragma unroll
                for (int o = 32; o > 0; o >>= 1) partial += __shfl_down(partial, o);
                if ((t & 63) == 0) redS[t >> 6] = partial;
                __syncthreads();
                float proj = redS[0] + redS[1] + redS[2] + redS[3];
                for (int j = t; j < TDIM; j += 256)
                    xcs[j] = x0s[j] * proj + p.crb[l * TDIM + j] + xcs[j];
                __syncthreads();
            }

            for (int j = 4 * t; j < KP1; j += 1024) {
                ushort4 sv;
                sv.x = (j + 0 < TDIM) ? f2bf(xcs[j + 0]) : 0;
                sv.y = (j + 1 < TDIM) ? f2bf(xcs[j + 1]) : 0;
                sv.z = (j + 2 < TDIM) ? f2bf(xcs[j + 2]) : 0;
                sv.w = (j + 3 < TDIM) ? f2bf(xcs[j + 3]) : 0;
                *(ushort4*)(p.XCb + (size_t)row * KP1 + j) = sv;
            }

            if (t < 32) {
                float h = p.ab1[t];
                #pragma unroll
                for (int e = 0; e < EDIM; e++) h += x0s[FEAT + e] * p.aW1[e * 32 + t];
                h = fmaxf(h, 0.f);
                float c = h * p.aW2[t];
                #pragma unroll
                for (int o = 16; o > 0; o >>= 1) c += __shfl_down(c, o, 32);
                if (t == 0) p.auxg[row] = c + p.ab2[0];
            }
        }
    }

    gbar(p.bar, 0);

    // ---------------- phase B: L1 GEMM ----------------
    {
        short* As = (short*)smem;
        short* Bs = As + 128 * 64;
        for (int id = blockIdx.x; id < L1_TILES; id += GRID) {
            int xn = id & 3, y = id >> 2;
            int n0 = xn * 128;
            if (y < 32) {
                gemm_tile(p.XCb, p.Wc1b, p.cb1, p.H1c, p.perm, 1,
                          y * 128, BATCH, n0, KP1, KP1, 512, 1, As, Bs);
            } else {
                int yy = y - 32;
                int d = yy >> 5, sl = yy & 31;
                int ds = p.starts[d], de = p.starts[d + 1];
                int m0 = ds + sl * 128;
                if (m0 < de)
                    gemm_tile(p.XCb, p.Wd1b + (size_t)d * 512 * KP1, p.db1 + d * 512,
                              p.H1d, p.perm, 1, m0, de, n0, KP1, KP1, 512, 1, As, Bs);
            }
        }
    }

    gbar(p.bar, 1);

    // ---------------- phase C: L2 GEMM ----------------
    {
        short* As = (short*)smem;
        short* Bs = As + 128 * 64;
        for (int id = blockIdx.x; id < L2_TILES; id += GRID) {
            int xn = id & 1, y = id >> 1;
            int n0 = xn * 128;
            if (y < 32) {
                gemm_tile(p.H1c, p.Wc2b, p.cb2, p.H2c, p.perm, 0,
                          y * 128, BATCH, n0, 512, 512, 256, 1, As, Bs);
            } else {
                int yy = y - 32;
                int d = yy >> 5, sl = yy & 31;
                int ds = p.starts[d], de = p.starts[d + 1];
                int m0 = ds + sl * 128;
                if (m0 < de)
                    gemm_tile(p.H1d, p.Wd2b + (size_t)d * 256 * 512, p.db2 + d * 256,
                              p.H2d, p.perm, 0, m0, de, n0, 512, 512, 256, 1, As, Bs);
            }
        }
    }

    gbar(p.bar, 2);

    // ---------------- phase D: L3 + STAR + final MLP + sigmoid ----------------
    for (int id = blockIdx.x; id < D_TILES; id += GRID) {
        __syncthreads();
        int d = id >> 7, sl = id & 127;
        int ds = p.starts[d], de = p.starts[d + 1];
        int m0 = ds + sl * 32;
        if (m0 < de) g3f_unit(p, d, m0, de, smem);
    }
}

extern "C" void kernel_launch(void* const* d_in, const int* in_sizes, int n_in,
                              void* d_out, int out_size, void* d_ws, size_t ws_size,
                              hipStream_t stream) {
    (void)in_sizes; (void)n_in; (void)out_size; (void)ws_size;

    char* base = (char*)d_ws;
    size_t o = 0;
    auto alloc = [&](size_t bytes) { char* q = base + o; o += (bytes + 255) & ~size_t(255); return q; };

    P p;
    p.x    = (const float*)d_in[0];
    p.dom  = (const int*)  d_in[1];
    p.pnw  = (const float*)d_in[2];
    p.pnb  = (const float*)d_in[3];
    p.demb = (const float*)d_in[4];
    p.crw  = (const float*)d_in[5];
    p.crb  = (const float*)d_in[6];
    p.cW1  = (const float*)d_in[7];
    p.cb1  = (const float*)d_in[8];
    p.cW2  = (const float*)d_in[9];
    p.cb2  = (const float*)d_in[10];
    p.cW3  = (const float*)d_in[11];
    p.cb3  = (const float*)d_in[12];
    p.dW1  = (const float*)d_in[13];
    p.db1  = (const float*)d_in[14];
    p.dW2  = (const float*)d_in[15];
    p.db2  = (const float*)d_in[16];
    p.dW3  = (const float*)d_in[17];
    p.db3  = (const float*)d_in[18];
    p.fW1  = (const float*)d_in[19];
    p.fb1  = (const float*)d_in[20];
    p.fW2  = (const float*)d_in[21];
    p.fb2  = (const float*)d_in[22];
    p.aW1  = (const float*)d_in[23];
    p.ab1  = (const float*)d_in[24];
    p.aW2  = (const float*)d_in[25];
    p.ab2  = (const float*)d_in[26];
    p.out  = (float*)d_out;

    p.bar    = (unsigned*)alloc(256);
    p.perm   = (int*)alloc(BATCH * 4);
    p.starts = (int*)alloc((NDOM + 1) * 4);
    p.auxg   = (float*)alloc(BATCH * 4);
    p.XCb  = (unsigned short*)alloc((size_t)BATCH * KP1 * 2);
    p.H1c  = (unsigned short*)alloc((size_t)BATCH * 512 * 2);
    p.H1d  = (unsigned short*)alloc((size_t)BATCH * 512 * 2);
    p.H2c  = (unsigned short*)alloc((size_t)BATCH * 256 * 2);
    p.H2d  = (unsigned short*)alloc((size_t)BATCH * 256 * 2);
    p.Wc1b = (unsigned short*)alloc((size_t)512 * KP1 * 2);
    p.Wd1b = (unsigned short*)alloc((size_t)NDOM * 512 * KP1 * 2);
    p.Wc2b = (unsigned short*)alloc((size_t)256 * 512 * 2);
    p.Wd2b = (unsigned short*)alloc((size_t)NDOM * 256 * 512 * 2);
    p.Wc3b = (unsigned short*)alloc((size_t)128 * 256 * 2);
    p.Wd3b = (unsigned short*)alloc((size_t)NDOM * 128 * 256 * 2);

    mega<<<dim3(GRID), dim3(256), 0, stream>>>(p);
}

// Round 10
// 225.813 us; speedup vs baseline: 2.2185x; 2.2185x over previous
//
#include <hip/hip_runtime.h>
#include <math.h>
#include <stdint.h>

#define BATCH 4096
#define FEAT  1024
#define EDIM  16
#define NDOM  8
#define TDIM  1040   // FEAT + EDIM
#define KP1   1088   // TDIM padded to multiple of 64
#define NLAYER 3
#define EPSV  1e-5f

typedef __attribute__((ext_vector_type(8))) short bf16x8;
typedef __attribute__((ext_vector_type(4))) float f32x4;

__device__ __forceinline__ unsigned short f2bf(float f) {
    union { float f; unsigned int u; } v; v.f = f;
    unsigned int u = v.u;
    return (unsigned short)((u + 0x7fffu + ((u >> 16) & 1u)) >> 16);
}
__device__ __forceinline__ float bf2f(unsigned short u) {
    union { unsigned int u; float f; } v; v.u = ((unsigned int)u) << 16; return v.f;
}
__device__ __forceinline__ void gload_lds16(const void* g, void* l) {
    __builtin_amdgcn_global_load_lds(
        (const __attribute__((address_space(1))) void*)(g),
        (__attribute__((address_space(3))) void*)(l), 16, 0, 0);
}

// 64x64 convert tiles
#define T_W1 136   // 17 ktiles * 8 ntiles (Kp=1088, N=512)
#define T_W2 32    // 8 * 4
#define T_W3 8     // 4 * 2
#define NCONV (T_W1*9 + T_W2*9 + T_W3*9)   // 1584

// ======== kernel 1: weight converts (blocks 0..NCONV-1) + grouping (block NCONV) ========
__global__ __launch_bounds__(256) void convert_group(
    const int* __restrict__ dom, int* __restrict__ perm, int* __restrict__ starts,
    const float* __restrict__ cW1, const float* __restrict__ dW1,
    const float* __restrict__ cW2, const float* __restrict__ dW2,
    const float* __restrict__ cW3, const float* __restrict__ dW3,
    unsigned short* __restrict__ Wc1b, unsigned short* __restrict__ Wd1b,
    unsigned short* __restrict__ Wc2b, unsigned short* __restrict__ Wd2b,
    unsigned short* __restrict__ Wc3b, unsigned short* __restrict__ Wd3b) {
    int b = blockIdx.x;
    int t = threadIdx.x;

    if (b >= NCONV) {
        __shared__ int cnt[NDOM];
        __shared__ int off[NDOM];
        if (t < NDOM) cnt[t] = 0;
        __syncthreads();
        for (int i = t; i < BATCH; i += 256) atomicAdd(&cnt[dom[i]], 1);
        __syncthreads();
        if (t == 0) {
            int s = 0;
            for (int d = 0; d < NDOM; d++) { off[d] = s; starts[d] = s; s += cnt[d]; }
            starts[NDOM] = s;
        }
        __syncthreads();
        for (int i = t; i < BATCH; i += 256) {
            int p = atomicAdd(&off[dom[i]], 1);
            perm[p] = i;
        }
        return;
    }

    // fp32 (K,N) -> bf16 (N,Kp); 64x64 tile; LDS pad 65 (conflict-free column reads)
    __shared__ float tile[64][65];
    const float* src; unsigned short* dst; int K, N, Kp, rr;
    if (b < T_W1)            { src = cW1; dst = Wc1b; K = TDIM; N = 512; Kp = KP1; rr = b; }
    else if (b < T_W1*9)     { int r = b - T_W1; int z = r / T_W1; rr = r % T_W1;
                               src = dW1 + (size_t)z * TDIM * 512; dst = Wd1b + (size_t)z * 512 * KP1;
                               K = TDIM; N = 512; Kp = KP1; }
    else if (b < T_W1*9+T_W2)   { src = cW2; dst = Wc2b; K = 512; N = 256; Kp = 512; rr = b - T_W1*9; }
    else if (b < T_W1*9+T_W2*9) { int r = b - (T_W1*9+T_W2); int z = r / T_W2; rr = r % T_W2;
                               src = dW2 + (size_t)z * 512 * 256; dst = Wd2b + (size_t)z * 256 * 512;
                               K = 512; N = 256; Kp = 512; }
    else if (b < T_W1*9+T_W2*9+T_W3) { src = cW3; dst = Wc3b; K = 256; N = 128; Kp = 256; rr = b - (T_W1*9+T_W2*9); }
    else                     { int r = b - (T_W1*9+T_W2*9+T_W3); int z = r / T_W3; rr = r % T_W3;
                               src = dW3 + (size_t)z * 256 * 128; dst = Wd3b + (size_t)z * 128 * 256;
                               K = 256; N = 128; Kp = 256; }
    int kt = Kp >> 6;
    int kb = rr % kt, nb = rr / kt;
    int k0 = kb * 64, n0 = nb * 64;
    #pragma unroll
    for (int i = 0; i < 4; i++) {
        int flat = t + i * 256;
        int kr = flat >> 4, c4 = flat & 15;
        int k = k0 + kr;
        float4 v = make_float4(0.f, 0.f, 0.f, 0.f);
        if (k < K) v = *(const float4*)(src + (size_t)k * N + n0 + c4 * 4);
        tile[kr][c4 * 4 + 0] = v.x;
        tile[kr][c4 * 4 + 1] = v.y;
        tile[kr][c4 * 4 + 2] = v.z;
        tile[kr][c4 * 4 + 3] = v.w;
    }
    __syncthreads();
    #pragma unroll
    for (int i = 0; i < 4; i++) {
        int flat = t + i * 256;
        int n = flat >> 4, kg = flat & 15;
        ushort4 sv;
        sv.x = f2bf(tile[kg * 4 + 0][n]);
        sv.y = f2bf(tile[kg * 4 + 1][n]);
        sv.z = f2bf(tile[kg * 4 + 2][n]);
        sv.w = f2bf(tile[kg * 4 + 3][n]);
        *(ushort4*)(dst + (size_t)(n0 + n) * Kp + k0 + kg * 4) = sv;
    }
}

// ======== kernel 2: prep, barrier-free — one wave per row, row in registers ========
__global__ __launch_bounds__(256) void prep_wave(
    const float* __restrict__ x, const int* __restrict__ dom,
    const float* __restrict__ pnw, const float* __restrict__ pnb,
    const float* __restrict__ demb,
    const float* __restrict__ crw, const float* __restrict__ crb,
    const float* __restrict__ aW1, const float* __restrict__ ab1,
    const float* __restrict__ aW2, const float* __restrict__ ab2,
    unsigned short* __restrict__ XCb, float* __restrict__ auxg) {
    int w = threadIdx.x >> 6, lane = threadIdx.x & 63;
    int row = blockIdx.x * 4 + w;
    int d = dom[row];

    float4 X[4];
    #pragma unroll
    for (int j = 0; j < 4; j++)
        X[j] = *(const float4*)(x + (size_t)row * FEAT + 4 * lane + 256 * j);

    float s = 0.f, ss = 0.f;
    #pragma unroll
    for (int j = 0; j < 4; j++) {
        s  += X[j].x + X[j].y + X[j].z + X[j].w;
        ss += X[j].x*X[j].x + X[j].y*X[j].y + X[j].z*X[j].z + X[j].w*X[j].w;
    }
    #pragma unroll
    for (int m = 1; m < 64; m <<= 1) {
        s  += __shfl_xor(s,  m);
        ss += __shfl_xor(ss, m);
    }
    float mean = s / (float)FEAT;
    float var  = ss / (float)FEAT - mean * mean;
    float rstd = rsqrtf(var + EPSV);

    float4 x0[4], xc[4];
    #pragma unroll
    for (int j = 0; j < 4; j++) {
        float4 wv = *(const float4*)(pnw + (size_t)d * FEAT + 4 * lane + 256 * j);
        float4 bv = *(const float4*)(pnb + (size_t)d * FEAT + 4 * lane + 256 * j);
        x0[j].x = (X[j].x - mean) * rstd * wv.x + bv.x;
        x0[j].y = (X[j].y - mean) * rstd * wv.y + bv.y;
        x0[j].z = (X[j].z - mean) * rstd * wv.z + bv.z;
        x0[j].w = (X[j].w - mean) * rstd * wv.w + bv.w;
        xc[j] = x0[j];
    }
    float x0e = 0.f, xce = 0.f;
    if (lane < EDIM) { x0e = demb[d * EDIM + lane]; xce = x0e; }

    #pragma unroll
    for (int l = 0; l < NLAYER; l++) {
        const float* wl = crw + l * TDIM;
        const float* bl = crb + l * TDIM;
        float partial = 0.f;
        #pragma unroll
        for (int j = 0; j < 4; j++) {
            float4 wv = *(const float4*)(wl + 4 * lane + 256 * j);
            partial += xc[j].x*wv.x + xc[j].y*wv.y + xc[j].z*wv.z + xc[j].w*wv.w;
        }
        if (lane < EDIM) partial += xce * wl[FEAT + lane];
        #pragma unroll
        for (int m = 1; m < 64; m <<= 1) partial += __shfl_xor(partial, m);
        float proj = partial;
        #pragma unroll
        for (int j = 0; j < 4; j++) {
            float4 bv = *(const float4*)(bl + 4 * lane + 256 * j);
            xc[j].x = fmaf(x0[j].x, proj, bv.x + xc[j].x);
            xc[j].y = fmaf(x0[j].y, proj, bv.y + xc[j].y);
            xc[j].z = fmaf(x0[j].z, proj, bv.z + xc[j].z);
            xc[j].w = fmaf(x0[j].w, proj, bv.w + xc[j].w);
        }
        if (lane < EDIM) xce = fmaf(x0e, proj, bl[FEAT + lane] + xce);
    }

    // store bf16 row (0..1023 vectorized; 1024..1087 scalar: e-part then zero pad)
    #pragma unroll
    for (int j = 0; j < 4; j++) {
        ushort4 sv;
        sv.x = f2bf(xc[j].x); sv.y = f2bf(xc[j].y);
        sv.z = f2bf(xc[j].z); sv.w = f2bf(xc[j].w);
        *(ushort4*)(XCb + (size_t)row * KP1 + 4 * lane + 256 * j) = sv;
    }
    XCb[(size_t)row * KP1 + FEAT + lane] = (lane < EDIM) ? f2bf(xce) : 0;

    // aux net: relu(e @ aW1 + ab1) @ aW2 + ab2
    float h = (lane < 32) ? ab1[lane] : 0.f;
    #pragma unroll
    for (int e = 0; e < EDIM; e++) {
        float ev = __shfl(xce, e);
        if (lane < 32) h = fmaf(ev, aW1[e * 32 + lane], h);
    }
    float c = (lane < 32) ? fmaxf(h, 0.f) * aW2[lane] : 0.f;
    #pragma unroll
    for (int m = 1; m < 64; m <<= 1) c += __shfl_xor(c, m);
    if (lane == 0) auxg[row] = c + ab2[0];
}

// ======== MFMA bf16 GEMM v2: 128x128 tile, BK=64, global_load_lds (best measured) ========
__global__ __launch_bounds__(256) void gemm_mfma_v2(
    const unsigned short* __restrict__ Ac, const unsigned short* __restrict__ Ad, int lda,
    const unsigned short* __restrict__ Wc, const unsigned short* __restrict__ Wd,
    const float* __restrict__ bc, const float* __restrict__ bd,
    unsigned short* __restrict__ Cc, unsigned short* __restrict__ Cd,
    const int* __restrict__ starts, const int* __restrict__ perm, int usePerm,
    int Kp, int N, int relu) {
    __shared__ short As[128 * 64];
    __shared__ short Bs[128 * 64];

    const unsigned short* A; const unsigned short* W; const float* bias;
    unsigned short* C;
    int m0, mEnd;
    int y = blockIdx.y;
    if (y < 32) {
        A = Ac; W = Wc; bias = bc; C = Cc;
        m0 = y * 128; mEnd = BATCH;
    } else {
        int yy = y - 32;
        int d = yy >> 5, sl = yy & 31;
        int ds = starts[d], de = starts[d + 1];
        m0 = ds + sl * 128;
        if (m0 >= de) return;
        mEnd = de;
        A = Ad; W = Wd + (size_t)d * N * Kp; bias = bd + d * N; C = Cd;
    }
    int n0 = blockIdx.x * 128;
    int tid = threadIdx.x;
    int w = tid >> 6, lane = tid & 63;
    int wm = w >> 1, wn = w & 1;
    int lr = lane & 15, q = lane >> 4;

    const unsigned short* pA[4]; const unsigned short* pB[4];
    short* dA[4]; short* dB[4];
    #pragma unroll
    for (int i = 0; i < 4; i++) {
        int seg = i * 4 + w;
        int ch = seg * 64 + lane;
        int loc = ch >> 3, c = ch & 7;
        int mm = m0 + loc; if (mm > mEnd - 1) mm = mEnd - 1;
        int row = usePerm ? perm[mm] : mm;
        pA[i] = A + (size_t)row * lda + ((c ^ (loc & 7)) << 3);
        dA[i] = As + seg * 512;
        pB[i] = W + (size_t)(n0 + loc) * Kp + ((c ^ (loc & 7)) << 3);
        dB[i] = Bs + seg * 512;
    }

    f32x4 acc[4][4];
    #pragma unroll
    for (int i = 0; i < 4; i++)
        #pragma unroll
        for (int j = 0; j < 4; j++)
            acc[i][j] = (f32x4){0.f, 0.f, 0.f, 0.f};

    for (int k0 = 0; k0 < Kp; k0 += 64) {
        #pragma unroll
        for (int i = 0; i < 4; i++) gload_lds16(pA[i] + k0, dA[i]);
        #pragma unroll
        for (int i = 0; i < 4; i++) gload_lds16(pB[i] + k0, dB[i]);
        __syncthreads();

        #pragma unroll
        for (int half = 0; half < 2; half++) {
            int c = half * 4 + q;
            bf16x8 af[4], bf[4];
            #pragma unroll
            for (int i = 0; i < 4; i++) {
                int m = wm * 64 + i * 16 + lr;
                af[i] = *(const bf16x8*)(As + m * 64 + ((c ^ (m & 7)) << 3));
            }
            #pragma unroll
            for (int j = 0; j < 4; j++) {
                int n = wn * 64 + j * 16 + lr;
                bf[j] = *(const bf16x8*)(Bs + n * 64 + ((c ^ (n & 7)) << 3));
            }
            #pragma unroll
            for (int i = 0; i < 4; i++)
                #pragma unroll
                for (int j = 0; j < 4; j++)
                    acc[i][j] = __builtin_amdgcn_mfma_f32_16x16x32_bf16(
                        af[i], bf[j], acc[i][j], 0, 0, 0);
        }
        __syncthreads();
    }

    #pragma unroll
    for (int i = 0; i < 4; i++) {
        #pragma unroll
        for (int j = 0; j < 4; j++) {
            int col = n0 + wn * 64 + j * 16 + lr;
            float bvv = bias[col];
            int rowb = m0 + wm * 64 + i * 16 + q * 4;
            #pragma unroll
            for (int r = 0; r < 4; r++) {
                int row = rowb + r;
                if (row >= mEnd) continue;
                float val = acc[i][j][r] + bvv;
                if (relu) val = fmaxf(val, 0.f);
                C[(size_t)row * N + col] = f2bf(val);
            }
        }
    }
}

// ======== fused layer-3 (64-row slots, R6-proven): both chains + STAR + final MLP + sigmoid ========
__global__ __launch_bounds__(256) void gemm3_final(
    const unsigned short* __restrict__ Ac, const unsigned short* __restrict__ Ad,
    const unsigned short* __restrict__ Wc, const unsigned short* __restrict__ Wd,
    const float* __restrict__ bc, const float* __restrict__ bd,
    const float* __restrict__ fW1, const float* __restrict__ fb1,
    const float* __restrict__ fW2, const float* __restrict__ fb2,
    const float* __restrict__ auxg, const int* __restrict__ perm,
    const int* __restrict__ starts, float* __restrict__ out) {
    __shared__ __align__(16) char smem[40960];
    short* As     = (short*)smem;
    short* Bs     = (short*)(smem + 8192);
    short* fusedB = (short*)(smem + 24576);

    int y = blockIdx.x;
    int d = y >> 6, sl = y & 63;
    int ds = starts[d], de = starts[d + 1];
    int m0 = ds + sl * 64;
    if (m0 >= de) return;
    int mEnd = de;

    int tid = threadIdx.x;
    int w = tid >> 6, lane = tid & 63;
    int wm = w >> 1, wn = w & 1;
    int lr = lane & 15, q = lane >> 4;
    const uint4 zero16 = make_uint4(0u, 0u, 0u, 0u);

    for (int chain = 0; chain < 2; chain++) {
        const unsigned short* A = chain ? Ad : Ac;
        const unsigned short* W = chain ? (Wd + (size_t)d * 128 * 256) : Wc;
        const float* bias = chain ? (bd + d * 128) : bc;
        f32x4 acc[2][4];
        #pragma unroll
        for (int i = 0; i < 2; i++)
            #pragma unroll
            for (int j = 0; j < 4; j++) acc[i][j] = (f32x4){0.f, 0.f, 0.f, 0.f};

        for (int k0 = 0; k0 < 256; k0 += 64) {
            #pragma unroll
            for (int i = 0; i < 2; i++) {
                int flat = tid + i * 256;
                int m = flat >> 3, c = flat & 7;
                int row = m0 + m;
                uint4 val = (row < mEnd)
                    ? *(const uint4*)(A + (size_t)row * 256 + k0 + c * 8) : zero16;
                *(uint4*)(As + m * 64 + ((c ^ (m & 7)) * 8)) = val;
            }
            #pragma unroll
            for (int i = 0; i < 4; i++) {
                int flat = tid + i * 256;
                int n = flat >> 3, c = flat & 7;
                uint4 val = *(const uint4*)(W + (size_t)n * 256 + k0 + c * 8);
                *(uint4*)(Bs + n * 64 + ((c ^ (n & 7)) * 8)) = val;
            }
            __syncthreads();
            #pragma unroll
            for (int g = 0; g < 2; g++) {
                int c = g * 4 + q;
                bf16x8 af[2], bf[4];
                #pragma unroll
                for (int i = 0; i < 2; i++) {
                    int m = wm * 32 + i * 16 + lr;
                    af[i] = *(const bf16x8*)(As + m * 64 + ((c ^ (m & 7)) * 8));
                }
                #pragma unroll
                for (int j = 0; j < 4; j++) {
                    int n = wn * 64 + j * 16 + lr;
                    bf[j] = *(const bf16x8*)(Bs + n * 64 + ((c ^ (n & 7)) * 8));
                }
                #pragma unroll
                for (int i = 0; i < 2; i++)
                    #pragma unroll
                    for (int j = 0; j < 4; j++)
                        acc[i][j] = __builtin_amdgcn_mfma_f32_16x16x32_bf16(
                            af[i], bf[j], acc[i][j], 0, 0, 0);
            }
            __syncthreads();
        }
        #pragma unroll
        for (int i = 0; i < 2; i++) {
            #pragma unroll
            for (int j = 0; j < 4; j++) {
                int col = wn * 64 + j * 16 + lr;
                float bvv = bias[col];
                int cch = col >> 3;
                #pragma unroll
                for (int r = 0; r < 4; r++) {
                    int row = wm * 32 + i * 16 + q * 4 + r;
                    int pc = (cch & 8) | ((cch ^ (row & 7)) & 7);
                    int idx = row * 128 + pc * 8 + (col & 7);
                    if (chain == 0) {
                        fusedB[idx] = (short)f2bf(acc[i][j][r] + bvv);
                    } else {
                        float cv = bf2f((unsigned short)fusedB[idx]);
                        fusedB[idx] = (short)f2bf(cv * tanhf(acc[i][j][r] + bvv));
                    }
                }
            }
        }
    }
    __syncthreads();

    short* Bsf = Bs;
    float* Ls  = (float*)As;
    for (int s2 = tid; s2 < 1024; s2 += 256) {
        int n = s2 >> 4, cch = s2 & 15;
        bf16x8 vv;
        #pragma unroll
        for (int kk = 0; kk < 8; kk++)
            vv[kk] = (short)f2bf(fW1[(cch * 8 + kk) * 64 + n]);
        int pc = (cch & 8) | ((cch ^ (n & 7)) & 7);
        *(bf16x8*)(Bsf + n * 128 + pc * 8) = vv;
    }
    __syncthreads();

    f32x4 acc2[2][2];
    #pragma unroll
    for (int i = 0; i < 2; i++)
        #pragma unroll
        for (int j = 0; j < 2; j++) acc2[i][j] = (f32x4){0.f, 0.f, 0.f, 0.f};
    #pragma unroll
    for (int g = 0; g < 4; g++) {
        int c = g * 4 + q;
        bf16x8 af[2], bf[2];
        #pragma unroll
        for (int i = 0; i < 2; i++) {
            int m = wm * 32 + i * 16 + lr;
            int pc = (c & 8) | ((c ^ (m & 7)) & 7);
            af[i] = *(const bf16x8*)(fusedB + m * 128 + pc * 8);
        }
        #pragma unroll
        for (int j = 0; j < 2; j++) {
            int n = wn * 32 + j * 16 + lr;
            int pc = (c & 8) | ((c ^ (n & 7)) & 7);
            bf[j] = *(const bf16x8*)(Bsf + n * 128 + pc * 8);
        }
        #pragma unroll
        for (int i = 0; i < 2; i++)
            #pragma unroll
            for (int j = 0; j < 2; j++)
                acc2[i][j] = __builtin_amdgcn_mfma_f32_16x16x32_bf16(
                    af[i], bf[j], acc2[i][j], 0, 0, 0);
    }

    float w2v[2], b1v[2];
    #pragma unroll
    for (int j = 0; j < 2; j++) {
        int col = wn * 32 + j * 16 + lr;
        w2v[j] = fW2[col];
        b1v[j] = fb1[col];
    }
    float rowv[2][4];
    #pragma unroll
    for (int i = 0; i < 2; i++)
        #pragma unroll
        for (int r = 0; r < 4; r++) {
            float v = 0.f;
            #pragma unroll
            for (int j = 0; j < 2; j++)
                v += fmaxf(acc2[i][j][r] + b1v[j], 0.f) * w2v[j];
            v += __shfl_xor(v, 1);
            v += __shfl_xor(v, 2);
            v += __shfl_xor(v, 4);
            v += __shfl_xor(v, 8);
            rowv[i][r] = v;
        }
    if (wn == 0 && lr == 0) {
        #pragma unroll
        for (int i = 0; i < 2; i++)
            #pragma unroll
            for (int r = 0; r < 4; r++)
                Ls[wm * 32 + i * 16 + q * 4 + r] = rowv[i][r];
    }
    __syncthreads();
    if (wn == 1 && lr == 0) {
        float b2 = fb2[0];
        #pragma unroll
        for (int i = 0; i < 2; i++)
            #pragma unroll
            for (int r = 0; r < 4; r++) {
                int row = wm * 32 + i * 16 + q * 4 + r;
                int p = m0 + row;
                if (p < mEnd) {
                    int orow = perm[p];
                    float logit = Ls[row] + rowv[i][r] + b2 + auxg[orow];
                    out[orow] = 1.f / (1.f + expf(-logit));
                }
            }
    }
}

extern "C" void kernel_launch(void* const* d_in, const int* in_sizes, int n_in,
                              void* d_out, int out_size, void* d_ws, size_t ws_size,
                              hipStream_t stream) {
    (void)in_sizes; (void)n_in; (void)out_size; (void)ws_size;

    const float* x    = (const float*)d_in[0];
    const int*   dom  = (const int*)  d_in[1];
    const float* pnw  = (const float*)d_in[2];
    const float* pnb  = (const float*)d_in[3];
    const float* demb = (const float*)d_in[4];
    const float* crw  = (const float*)d_in[5];
    const float* crb  = (const float*)d_in[6];
    const float* cW1  = (const float*)d_in[7];
    const float* cb1  = (const float*)d_in[8];
    const float* cW2  = (const float*)d_in[9];
    const float* cb2  = (const float*)d_in[10];
    const float* cW3  = (const float*)d_in[11];
    const float* cb3  = (const float*)d_in[12];
    const float* dW1  = (const float*)d_in[13];
    const float* db1  = (const float*)d_in[14];
    const float* dW2  = (const float*)d_in[15];
    const float* db2  = (const float*)d_in[16];
    const float* dW3  = (const float*)d_in[17];
    const float* db3  = (const float*)d_in[18];
    const float* fW1  = (const float*)d_in[19];
    const float* fb1  = (const float*)d_in[20];
    const float* fW2  = (const float*)d_in[21];
    const float* fb2  = (const float*)d_in[22];
    const float* aW1  = (const float*)d_in[23];
    const float* ab1  = (const float*)d_in[24];
    const float* aW2  = (const float*)d_in[25];
    const float* ab2  = (const float*)d_in[26];
    float* out = (float*)d_out;

    char* base = (char*)d_ws;
    size_t o = 0;
    auto alloc = [&](size_t bytes) { char* p = base + o; o += (bytes + 255) & ~size_t(255); return p; };

    int* perm   = (int*)alloc(BATCH * 4);
    int* starts = (int*)alloc((NDOM + 1) * 4);
    float* auxg = (float*)alloc(BATCH * 4);
    unsigned short* XCb  = (unsigned short*)alloc((size_t)BATCH * KP1 * 2);
    unsigned short* H1c  = (unsigned short*)alloc((size_t)BATCH * 512 * 2);
    unsigned short* H1d  = (unsigned short*)alloc((size_t)BATCH * 512 * 2);
    unsigned short* H2c  = (unsigned short*)alloc((size_t)BATCH * 256 * 2);
    unsigned short* H2d  = (unsigned short*)alloc((size_t)BATCH * 256 * 2);
    unsigned short* Wc1b = (unsigned short*)alloc((size_t)512 * KP1 * 2);
    unsigned short* Wd1b = (unsigned short*)alloc((size_t)NDOM * 512 * KP1 * 2);
    unsigned short* Wc2b = (unsigned short*)alloc((size_t)256 * 512 * 2);
    unsigned short* Wd2b = (unsigned short*)alloc((size_t)NDOM * 256 * 512 * 2);
    unsigned short* Wc3b = (unsigned short*)alloc((size_t)128 * 256 * 2);
    unsigned short* Wd3b = (unsigned short*)alloc((size_t)NDOM * 128 * 256 * 2);

    // 1) weight convert + grouping
    convert_group<<<NCONV + 1, 256, 0, stream>>>(dom, perm, starts,
                                                 cW1, dW1, cW2, dW2, cW3, dW3,
                                                 Wc1b, Wd1b, Wc2b, Wd2b, Wc3b, Wd3b);
    // 2) prep (barrier-free, one wave per row)
    prep_wave<<<BATCH / 4, 256, 0, stream>>>(x, dom, pnw, pnb, demb, crw, crb,
                                             aW1, ab1, aW2, ab2, XCb, auxg);
    // 3) L1: (4096 x 1088) -> 512, relu (A gathered via perm)
    gemm_mfma_v2<<<dim3(512 / 128, 32 + NDOM * 32), 256, 0, stream>>>(
        XCb, XCb, KP1, Wc1b, Wd1b, cb1, db1, H1c, H1d, starts, perm, 1, KP1, 512, 1);
    // 4) L2: (4096 x 512) -> 256, relu
    gemm_mfma_v2<<<dim3(256 / 128, 32 + NDOM * 32), 256, 0, stream>>>(
        H1c, H1d, 512, Wc2b, Wd2b, cb2, db2, H2c, H2d, starts, perm, 0, 512, 256, 1);
    // 5) L3 + STAR + final MLP + sigmoid
    gemm3_final<<<NDOM * 64, 256, 0, stream>>>(
        H2c, H2d, Wc3b, Wd3b, cb3, db3, fW1, fb1, fW2, fb2,
        auxg, perm, starts, out);
}

// Round 11
// 216.667 us; speedup vs baseline: 2.3122x; 1.0422x over previous
//
#include <hip/hip_runtime.h>
#include <math.h>
#include <stdint.h>

#define BATCH 4096
#define FEAT  1024
#define EDIM  16
#define NDOM  8
#define TDIM  1040   // FEAT + EDIM
#define KP1   1088   // TDIM padded to multiple of 64
#define NLAYER 3
#define EPSV  1e-5f

typedef __attribute__((ext_vector_type(8))) short bf16x8;
typedef __attribute__((ext_vector_type(4))) float f32x4;

__device__ __forceinline__ unsigned short f2bf(float f) {
    union { float f; unsigned int u; } v; v.f = f;
    unsigned int u = v.u;
    return (unsigned short)((u + 0x7fffu + ((u >> 16) & 1u)) >> 16);
}
__device__ __forceinline__ float bf2f(unsigned short u) {
    union { unsigned int u; float f; } v; v.u = ((unsigned int)u) << 16; return v.f;
}
__device__ __forceinline__ void gload_lds16(const void* g, void* l) {
    __builtin_amdgcn_global_load_lds(
        (const __attribute__((address_space(1))) void*)(g),
        (__attribute__((address_space(3))) void*)(l), 16, 0, 0);
}

// 64x64 convert tiles
#define T_W1 136   // 17 ktiles * 8 ntiles (Kp=1088, N=512)
#define T_W2 32    // 8 * 4
#define T_W3 8     // 4 * 2
#define NCONV (T_W1*9 + T_W2*9 + T_W3*9)   // 1584

// ======== kernel 1 "front": converts (0..NCONV-1) + grouping (NCONV) + prep (NCONV+1 ..) ========
__global__ __launch_bounds__(256) void front(
    const int* __restrict__ dom, int* __restrict__ perm, int* __restrict__ starts,
    const float* __restrict__ cW1, const float* __restrict__ dW1,
    const float* __restrict__ cW2, const float* __restrict__ dW2,
    const float* __restrict__ cW3, const float* __restrict__ dW3,
    unsigned short* __restrict__ Wc1b, unsigned short* __restrict__ Wd1b,
    unsigned short* __restrict__ Wc2b, unsigned short* __restrict__ Wd2b,
    unsigned short* __restrict__ Wc3b, unsigned short* __restrict__ Wd3b,
    const float* __restrict__ x,
    const float* __restrict__ pnw, const float* __restrict__ pnb,
    const float* __restrict__ demb,
    const float* __restrict__ crw, const float* __restrict__ crb,
    const float* __restrict__ aW1, const float* __restrict__ ab1,
    const float* __restrict__ aW2, const float* __restrict__ ab2,
    unsigned short* __restrict__ XCb, float* __restrict__ auxg) {
    int b = blockIdx.x;
    int t = threadIdx.x;

    if (b < NCONV) {
        // ---- weight convert: fp32 (K,N) -> bf16 (N,Kp); 64x64 tile, pad 65 (conflict-free) ----
        __shared__ float tile[64][65];
        const float* src; unsigned short* dst; int K, N, Kp, rr;
        if (b < T_W1)            { src = cW1; dst = Wc1b; K = TDIM; N = 512; Kp = KP1; rr = b; }
        else if (b < T_W1*9)     { int r = b - T_W1; int z = r / T_W1; rr = r % T_W1;
                                   src = dW1 + (size_t)z * TDIM * 512; dst = Wd1b + (size_t)z * 512 * KP1;
                                   K = TDIM; N = 512; Kp = KP1; }
        else if (b < T_W1*9+T_W2)   { src = cW2; dst = Wc2b; K = 512; N = 256; Kp = 512; rr = b - T_W1*9; }
        else if (b < T_W1*9+T_W2*9) { int r = b - (T_W1*9+T_W2); int z = r / T_W2; rr = r % T_W2;
                                   src = dW2 + (size_t)z * 512 * 256; dst = Wd2b + (size_t)z * 256 * 512;
                                   K = 512; N = 256; Kp = 512; }
        else if (b < T_W1*9+T_W2*9+T_W3) { src = cW3; dst = Wc3b; K = 256; N = 128; Kp = 256; rr = b - (T_W1*9+T_W2*9); }
        else                     { int r = b - (T_W1*9+T_W2*9+T_W3); int z = r / T_W3; rr = r % T_W3;
                                   src = dW3 + (size_t)z * 256 * 128; dst = Wd3b + (size_t)z * 128 * 256;
                                   K = 256; N = 128; Kp = 256; }
        int kt = Kp >> 6;
        int kb = rr % kt, nb = rr / kt;
        int k0 = kb * 64, n0 = nb * 64;
        #pragma unroll
        for (int i = 0; i < 4; i++) {
            int flat = t + i * 256;
            int kr = flat >> 4, c4 = flat & 15;
            int k = k0 + kr;
            float4 v = make_float4(0.f, 0.f, 0.f, 0.f);
            if (k < K) v = *(const float4*)(src + (size_t)k * N + n0 + c4 * 4);
            tile[kr][c4 * 4 + 0] = v.x;
            tile[kr][c4 * 4 + 1] = v.y;
            tile[kr][c4 * 4 + 2] = v.z;
            tile[kr][c4 * 4 + 3] = v.w;
        }
        __syncthreads();
        #pragma unroll
        for (int i = 0; i < 4; i++) {
            int flat = t + i * 256;
            int n = flat >> 4, kg = flat & 15;
            ushort4 sv;
            sv.x = f2bf(tile[kg * 4 + 0][n]);
            sv.y = f2bf(tile[kg * 4 + 1][n]);
            sv.z = f2bf(tile[kg * 4 + 2][n]);
            sv.w = f2bf(tile[kg * 4 + 3][n]);
            *(ushort4*)(dst + (size_t)(n0 + n) * Kp + k0 + kg * 4) = sv;
        }
        return;
    }
    if (b == NCONV) {
        // ---- grouping ----
        __shared__ int cnt[NDOM];
        __shared__ int off[NDOM];
        if (t < NDOM) cnt[t] = 0;
        __syncthreads();
        for (int i = t; i < BATCH; i += 256) atomicAdd(&cnt[dom[i]], 1);
        __syncthreads();
        if (t == 0) {
            int s = 0;
            for (int d = 0; d < NDOM; d++) { off[d] = s; starts[d] = s; s += cnt[d]; }
            starts[NDOM] = s;
        }
        __syncthreads();
        for (int i = t; i < BATCH; i += 256) {
            int p = atomicAdd(&off[dom[i]], 1);
            perm[p] = i;
        }
        return;
    }

    // ---- prep: one wave per row, row in registers, barrier-free ----
    int w = t >> 6, lane = t & 63;
    int row = (b - NCONV - 1) * 4 + w;
    int d = dom[row];

    float4 X[4];
    #pragma unroll
    for (int j = 0; j < 4; j++)
        X[j] = *(const float4*)(x + (size_t)row * FEAT + 4 * lane + 256 * j);

    float s = 0.f, ss = 0.f;
    #pragma unroll
    for (int j = 0; j < 4; j++) {
        s  += X[j].x + X[j].y + X[j].z + X[j].w;
        ss += X[j].x*X[j].x + X[j].y*X[j].y + X[j].z*X[j].z + X[j].w*X[j].w;
    }
    #pragma unroll
    for (int m = 1; m < 64; m <<= 1) {
        s  += __shfl_xor(s,  m);
        ss += __shfl_xor(ss, m);
    }
    float mean = s / (float)FEAT;
    float var  = ss / (float)FEAT - mean * mean;
    float rstd = rsqrtf(var + EPSV);

    float4 x0[4], xc[4];
    #pragma unroll
    for (int j = 0; j < 4; j++) {
        float4 wv = *(const float4*)(pnw + (size_t)d * FEAT + 4 * lane + 256 * j);
        float4 bv = *(const float4*)(pnb + (size_t)d * FEAT + 4 * lane + 256 * j);
        x0[j].x = (X[j].x - mean) * rstd * wv.x + bv.x;
        x0[j].y = (X[j].y - mean) * rstd * wv.y + bv.y;
        x0[j].z = (X[j].z - mean) * rstd * wv.z + bv.z;
        x0[j].w = (X[j].w - mean) * rstd * wv.w + bv.w;
        xc[j] = x0[j];
    }
    float x0e = 0.f, xce = 0.f;
    if (lane < EDIM) { x0e = demb[d * EDIM + lane]; xce = x0e; }

    #pragma unroll
    for (int l = 0; l < NLAYER; l++) {
        const float* wl = crw + l * TDIM;
        const float* bl = crb + l * TDIM;
        float partial = 0.f;
        #pragma unroll
        for (int j = 0; j < 4; j++) {
            float4 wv = *(const float4*)(wl + 4 * lane + 256 * j);
            partial += xc[j].x*wv.x + xc[j].y*wv.y + xc[j].z*wv.z + xc[j].w*wv.w;
        }
        if (lane < EDIM) partial += xce * wl[FEAT + lane];
        #pragma unroll
        for (int m = 1; m < 64; m <<= 1) partial += __shfl_xor(partial, m);
        float proj = partial;
        #pragma unroll
        for (int j = 0; j < 4; j++) {
            float4 bv = *(const float4*)(bl + 4 * lane + 256 * j);
            xc[j].x = fmaf(x0[j].x, proj, bv.x + xc[j].x);
            xc[j].y = fmaf(x0[j].y, proj, bv.y + xc[j].y);
            xc[j].z = fmaf(x0[j].z, proj, bv.z + xc[j].z);
            xc[j].w = fmaf(x0[j].w, proj, bv.w + xc[j].w);
        }
        if (lane < EDIM) xce = fmaf(x0e, proj, bl[FEAT + lane] + xce);
    }

    #pragma unroll
    for (int j = 0; j < 4; j++) {
        ushort4 sv;
        sv.x = f2bf(xc[j].x); sv.y = f2bf(xc[j].y);
        sv.z = f2bf(xc[j].z); sv.w = f2bf(xc[j].w);
        *(ushort4*)(XCb + (size_t)row * KP1 + 4 * lane + 256 * j) = sv;
    }
    XCb[(size_t)row * KP1 + FEAT + lane] = (lane < EDIM) ? f2bf(xce) : 0;

    float h = (lane < 32) ? ab1[lane] : 0.f;
    #pragma unroll
    for (int e = 0; e < EDIM; e++) {
        float ev = __shfl(xce, e);
        if (lane < 32) h = fmaf(ev, aW1[e * 32 + lane], h);
    }
    float c = (lane < 32) ? fmaxf(h, 0.f) * aW2[lane] : 0.f;
    #pragma unroll
    for (int m = 1; m < 64; m <<= 1) c += __shfl_xor(c, m);
    if (lane == 0) auxg[row] = c + ab2[0];
}

// ======== MFMA bf16 GEMM: 128x64 tile, BK=64, global_load_lds (2x block count vs 128x128) ========
__global__ __launch_bounds__(256) void gemm_mfma_v3(
    const unsigned short* __restrict__ Ac, const unsigned short* __restrict__ Ad, int lda,
    const unsigned short* __restrict__ Wc, const unsigned short* __restrict__ Wd,
    const float* __restrict__ bc, const float* __restrict__ bd,
    unsigned short* __restrict__ Cc, unsigned short* __restrict__ Cd,
    const int* __restrict__ starts, const int* __restrict__ perm, int usePerm,
    int Kp, int N, int relu) {
    __shared__ short As[128 * 64];   // 16KB
    __shared__ short Bs[64 * 64];    // 8KB

    const unsigned short* A; const unsigned short* W; const float* bias;
    unsigned short* C;
    int m0, mEnd;
    int y = blockIdx.y;
    if (y < 32) {
        A = Ac; W = Wc; bias = bc; C = Cc;
        m0 = y * 128; mEnd = BATCH;
    } else {
        int yy = y - 32;
        int d = yy >> 5, sl = yy & 31;
        int ds = starts[d], de = starts[d + 1];
        m0 = ds + sl * 128;
        if (m0 >= de) return;
        mEnd = de;
        A = Ad; W = Wd + (size_t)d * N * Kp; bias = bd + d * N; C = Cd;
    }
    int n0 = blockIdx.x * 64;
    int tid = threadIdx.x;
    int w = tid >> 6, lane = tid & 63;
    int wm = w >> 1, wn = w & 1;
    int lr = lane & 15, q = lane >> 4;

    const unsigned short* pA[4]; const unsigned short* pB[2];
    short* dA[4]; short* dB[2];
    #pragma unroll
    for (int i = 0; i < 4; i++) {
        int seg = i * 4 + w;
        int ch = seg * 64 + lane;
        int loc = ch >> 3, c = ch & 7;
        int mm = m0 + loc; if (mm > mEnd - 1) mm = mEnd - 1;
        int rowp = usePerm ? perm[mm] : mm;
        pA[i] = A + (size_t)rowp * lda + ((c ^ (loc & 7)) << 3);
        dA[i] = As + seg * 512;
    }
    #pragma unroll
    for (int i = 0; i < 2; i++) {
        int seg = i * 4 + w;
        int ch = seg * 64 + lane;
        int loc = ch >> 3, c = ch & 7;
        pB[i] = W + (size_t)(n0 + loc) * Kp + ((c ^ (loc & 7)) << 3);
        dB[i] = Bs + seg * 512;
    }

    f32x4 acc[4][2];
    #pragma unroll
    for (int i = 0; i < 4; i++)
        #pragma unroll
        for (int j = 0; j < 2; j++)
            acc[i][j] = (f32x4){0.f, 0.f, 0.f, 0.f};

    for (int k0 = 0; k0 < Kp; k0 += 64) {
        #pragma unroll
        for (int i = 0; i < 4; i++) gload_lds16(pA[i] + k0, dA[i]);
        #pragma unroll
        for (int i = 0; i < 2; i++) gload_lds16(pB[i] + k0, dB[i]);
        __syncthreads();

        #pragma unroll
        for (int half = 0; half < 2; half++) {
            int c = half * 4 + q;
            bf16x8 af[4], bf[2];
            #pragma unroll
            for (int i = 0; i < 4; i++) {
                int m = wm * 64 + i * 16 + lr;
                af[i] = *(const bf16x8*)(As + m * 64 + ((c ^ (m & 7)) << 3));
            }
            #pragma unroll
            for (int j = 0; j < 2; j++) {
                int n = wn * 32 + j * 16 + lr;
                bf[j] = *(const bf16x8*)(Bs + n * 64 + ((c ^ (n & 7)) << 3));
            }
            #pragma unroll
            for (int i = 0; i < 4; i++)
                #pragma unroll
                for (int j = 0; j < 2; j++)
                    acc[i][j] = __builtin_amdgcn_mfma_f32_16x16x32_bf16(
                        af[i], bf[j], acc[i][j], 0, 0, 0);
        }
        __syncthreads();
    }

    #pragma unroll
    for (int i = 0; i < 4; i++) {
        #pragma unroll
        for (int j = 0; j < 2; j++) {
            int col = n0 + wn * 32 + j * 16 + lr;
            float bvv = bias[col];
            int rowb = m0 + wm * 64 + i * 16 + q * 4;
            #pragma unroll
            for (int r = 0; r < 4; r++) {
                int row = rowb + r;
                if (row >= mEnd) continue;
                float val = acc[i][j][r] + bvv;
                if (relu) val = fmaxf(val, 0.f);
                C[(size_t)row * N + col] = f2bf(val);
            }
        }
    }
}

// ======== fused layer-3 (64-row slots, R10-proven): both chains + STAR + final MLP + sigmoid ========
__global__ __launch_bounds__(256) void gemm3_final(
    const unsigned short* __restrict__ Ac, const unsigned short* __restrict__ Ad,
    const unsigned short* __restrict__ Wc, const unsigned short* __restrict__ Wd,
    const float* __restrict__ bc, const float* __restrict__ bd,
    const float* __restrict__ fW1, const float* __restrict__ fb1,
    const float* __restrict__ fW2, const float* __restrict__ fb2,
    const float* __restrict__ auxg, const int* __restrict__ perm,
    const int* __restrict__ starts, float* __restrict__ out) {
    __shared__ __align__(16) char smem[40960];
    short* As     = (short*)smem;
    short* Bs     = (short*)(smem + 8192);
    short* fusedB = (short*)(smem + 24576);

    int y = blockIdx.x;
    int d = y >> 6, sl = y & 63;
    int ds = starts[d], de = starts[d + 1];
    int m0 = ds + sl * 64;
    if (m0 >= de) return;
    int mEnd = de;

    int tid = threadIdx.x;
    int w = tid >> 6, lane = tid & 63;
    int wm = w >> 1, wn = w & 1;
    int lr = lane & 15, q = lane >> 4;
    const uint4 zero16 = make_uint4(0u, 0u, 0u, 0u);

    for (int chain = 0; chain < 2; chain++) {
        const unsigned short* A = chain ? Ad : Ac;
        const unsigned short* W = chain ? (Wd + (size_t)d * 128 * 256) : Wc;
        const float* bias = chain ? (bd + d * 128) : bc;
        f32x4 acc[2][4];
        #pragma unroll
        for (int i = 0; i < 2; i++)
            #pragma unroll
            for (int j = 0; j < 4; j++) acc[i][j] = (f32x4){0.f, 0.f, 0.f, 0.f};

        for (int k0 = 0; k0 < 256; k0 += 64) {
            #pragma unroll
            for (int i = 0; i < 2; i++) {
                int flat = tid + i * 256;
                int m = flat >> 3, c = flat & 7;
                int row = m0 + m;
                uint4 val = (row < mEnd)
                    ? *(const uint4*)(A + (size_t)row * 256 + k0 + c * 8) : zero16;
                *(uint4*)(As + m * 64 + ((c ^ (m & 7)) * 8)) = val;
            }
            #pragma unroll
            for (int i = 0; i < 4; i++) {
                int flat = tid + i * 256;
                int n = flat >> 3, c = flat & 7;
                uint4 val = *(const uint4*)(W + (size_t)n * 256 + k0 + c * 8);
                *(uint4*)(Bs + n * 64 + ((c ^ (n & 7)) * 8)) = val;
            }
            __syncthreads();
            #pragma unroll
            for (int g = 0; g < 2; g++) {
                int c = g * 4 + q;
                bf16x8 af[2], bf[4];
                #pragma unroll
                for (int i = 0; i < 2; i++) {
                    int m = wm * 32 + i * 16 + lr;
                    af[i] = *(const bf16x8*)(As + m * 64 + ((c ^ (m & 7)) * 8));
                }
                #pragma unroll
                for (int j = 0; j < 4; j++) {
                    int n = wn * 64 + j * 16 + lr;
                    bf[j] = *(const bf16x8*)(Bs + n * 64 + ((c ^ (n & 7)) * 8));
                }
                #pragma unroll
                for (int i = 0; i < 2; i++)
                    #pragma unroll
                    for (int j = 0; j < 4; j++)
                        acc[i][j] = __builtin_amdgcn_mfma_f32_16x16x32_bf16(
                            af[i], bf[j], acc[i][j], 0, 0, 0);
            }
            __syncthreads();
        }
        #pragma unroll
        for (int i = 0; i < 2; i++) {
            #pragma unroll
            for (int j = 0; j < 4; j++) {
                int col = wn * 64 + j * 16 + lr;
                float bvv = bias[col];
                int cch = col >> 3;
                #pragma unroll
                for (int r = 0; r < 4; r++) {
                    int row = wm * 32 + i * 16 + q * 4 + r;
                    int pc = (cch & 8) | ((cch ^ (row & 7)) & 7);
                    int idx = row * 128 + pc * 8 + (col & 7);
                    if (chain == 0) {
                        fusedB[idx] = (short)f2bf(acc[i][j][r] + bvv);
                    } else {
                        float cv = bf2f((unsigned short)fusedB[idx]);
                        fusedB[idx] = (short)f2bf(cv * tanhf(acc[i][j][r] + bvv));
                    }
                }
            }
        }
    }
    __syncthreads();

    short* Bsf = Bs;
    float* Ls  = (float*)As;
    for (int s2 = tid; s2 < 1024; s2 += 256) {
        int n = s2 >> 4, cch = s2 & 15;
        bf16x8 vv;
        #pragma unroll
        for (int kk = 0; kk < 8; kk++)
            vv[kk] = (short)f2bf(fW1[(cch * 8 + kk) * 64 + n]);
        int pc = (cch & 8) | ((cch ^ (n & 7)) & 7);
        *(bf16x8*)(Bsf + n * 128 + pc * 8) = vv;
    }
    __syncthreads();

    f32x4 acc2[2][2];
    #pragma unroll
    for (int i = 0; i < 2; i++)
        #pragma unroll
        for (int j = 0; j < 2; j++) acc2[i][j] = (f32x4){0.f, 0.f, 0.f, 0.f};
    #pragma unroll
    for (int g = 0; g < 4; g++) {
        int c = g * 4 + q;
        bf16x8 af[2], bf[2];
        #pragma unroll
        for (int i = 0; i < 2; i++) {
            int m = wm * 32 + i * 16 + lr;
            int pc = (c & 8) | ((c ^ (m & 7)) & 7);
            af[i] = *(const bf16x8*)(fusedB + m * 128 + pc * 8);
        }
        #pragma unroll
        for (int j = 0; j < 2; j++) {
            int n = wn * 32 + j * 16 + lr;
            int pc = (c & 8) | ((c ^ (n & 7)) & 7);
            bf[j] = *(const bf16x8*)(Bsf + n * 128 + pc * 8);
        }
        #pragma unroll
        for (int i = 0; i < 2; i++)
            #pragma unroll
            for (int j = 0; j < 2; j++)
                acc2[i][j] = __builtin_amdgcn_mfma_f32_16x16x32_bf16(
                    af[i], bf[j], acc2[i][j], 0, 0, 0);
    }

    float w2v[2], b1v[2];
    #pragma unroll
    for (int j = 0; j < 2; j++) {
        int col = wn * 32 + j * 16 + lr;
        w2v[j] = fW2[col];
        b1v[j] = fb1[col];
    }
    float rowv[2][4];
    #pragma unroll
    for (int i = 0; i < 2; i++)
        #pragma unroll
        for (int r = 0; r < 4; r++) {
            float v = 0.f;
            #pragma unroll
            for (int j = 0; j < 2; j++)
                v += fmaxf(acc2[i][j][r] + b1v[j], 0.f) * w2v[j];
            v += __shfl_xor(v, 1);
            v += __shfl_xor(v, 2);
            v += __shfl_xor(v, 4);
            v += __shfl_xor(v, 8);
            rowv[i][r] = v;
        }
    if (wn == 0 && lr == 0) {
        #pragma unroll
        for (int i = 0; i < 2; i++)
            #pragma unroll
            for (int r = 0; r < 4; r++)
                Ls[wm * 32 + i * 16 + q * 4 + r] = rowv[i][r];
    }
    __syncthreads();
    if (wn == 1 && lr == 0) {
        float b2 = fb2[0];
        #pragma unroll
        for (int i = 0; i < 2; i++)
            #pragma unroll
            for (int r = 0; r < 4; r++) {
                int row = wm * 32 + i * 16 + q * 4 + r;
                int p = m0 + row;
                if (p < mEnd) {
                    int orow = perm[p];
                    float logit = Ls[row] + rowv[i][r] + b2 + auxg[orow];
                    out[orow] = 1.f / (1.f + expf(-logit));
                }
            }
    }
}

extern "C" void kernel_launch(void* const* d_in, const int* in_sizes, int n_in,
                              void* d_out, int out_size, void* d_ws, size_t ws_size,
                              hipStream_t stream) {
    (void)in_sizes; (void)n_in; (void)out_size; (void)ws_size;

    const float* x    = (const float*)d_in[0];
    const int*   dom  = (const int*)  d_in[1];
    const float* pnw  = (const float*)d_in[2];
    const float* pnb  = (const float*)d_in[3];
    const float* demb = (const float*)d_in[4];
    const float* crw  = (const float*)d_in[5];
    const float* crb  = (const float*)d_in[6];
    const float* cW1  = (const float*)d_in[7];
    const float* cb1  = (const float*)d_in[8];
    const float* cW2  = (const float*)d_in[9];
    const float* cb2  = (const float*)d_in[10];
    const float* cW3  = (const float*)d_in[11];
    const float* cb3  = (const float*)d_in[12];
    const float* dW1  = (const float*)d_in[13];
    const float* db1  = (const float*)d_in[14];
    const float* dW2  = (const float*)d_in[15];
    const float* db2  = (const float*)d_in[16];
    const float* dW3  = (const float*)d_in[17];
    const float* db3  = (const float*)d_in[18];
    const float* fW1  = (const float*)d_in[19];
    const float* fb1  = (const float*)d_in[20];
    const float* fW2  = (const float*)d_in[21];
    const float* fb2  = (const float*)d_in[22];
    const float* aW1  = (const float*)d_in[23];
    const float* ab1  = (const float*)d_in[24];
    const float* aW2  = (const float*)d_in[25];
    const float* ab2  = (const float*)d_in[26];
    float* out = (float*)d_out;

    char* base = (char*)d_ws;
    size_t o = 0;
    auto alloc = [&](size_t bytes) { char* p = base + o; o += (bytes + 255) & ~size_t(255); return p; };

    int* perm   = (int*)alloc(BATCH * 4);
    int* starts = (int*)alloc((NDOM + 1) * 4);
    float* auxg = (float*)alloc(BATCH * 4);
    unsigned short* XCb  = (unsigned short*)alloc((size_t)BATCH * KP1 * 2);
    unsigned short* H1c  = (unsigned short*)alloc((size_t)BATCH * 512 * 2);
    unsigned short* H1d  = (unsigned short*)alloc((size_t)BATCH * 512 * 2);
    unsigned short* H2c  = (unsigned short*)alloc((size_t)BATCH * 256 * 2);
    unsigned short* H2d  = (unsigned short*)alloc((size_t)BATCH * 256 * 2);
    unsigned short* Wc1b = (unsigned short*)alloc((size_t)512 * KP1 * 2);
    unsigned short* Wd1b = (unsigned short*)alloc((size_t)NDOM * 512 * KP1 * 2);
    unsigned short* Wc2b = (unsigned short*)alloc((size_t)256 * 512 * 2);
    unsigned short* Wd2b = (unsigned short*)alloc((size_t)NDOM * 256 * 512 * 2);
    unsigned short* Wc3b = (unsigned short*)alloc((size_t)128 * 256 * 2);
    unsigned short* Wd3b = (unsigned short*)alloc((size_t)NDOM * 128 * 256 * 2);

    // 1) convert + grouping + prep (one launch)
    front<<<NCONV + 1 + BATCH / 4, 256, 0, stream>>>(
        dom, perm, starts, cW1, dW1, cW2, dW2, cW3, dW3,
        Wc1b, Wd1b, Wc2b, Wd2b, Wc3b, Wd3b,
        x, pnw, pnb, demb, crw, crb, aW1, ab1, aW2, ab2, XCb, auxg);

    // 2) L1: (4096 x 1088) -> 512, relu (A gathered via perm), 128x64 tiles (576 useful blocks)
    gemm_mfma_v3<<<dim3(512 / 64, 32 + NDOM * 32), 256, 0, stream>>>(
        XCb, XCb, KP1, Wc1b, Wd1b, cb1, db1, H1c, H1d, starts, perm, 1, KP1, 512, 1);
    // 3) L2: (4096 x 512) -> 256, relu, 128x64 tiles
    gemm_mfma_v3<<<dim3(256 / 64, 32 + NDOM * 32), 256, 0, stream>>>(
        H1c, H1d, 512, Wc2b, Wd2b, cb2, db2, H2c, H2d, starts, perm, 0, 512, 256, 1);

    // 4) L3 + STAR + final MLP + sigmoid
    gemm3_final<<<NDOM * 64, 256, 0, stream>>>(
        H2c, H2d, Wc3b, Wd3b, cb3, db3, fW1, fb1, fW2, fb2,
        auxg, perm, starts, out);
}

// Round 12
// 205.707 us; speedup vs baseline: 2.4354x; 1.0533x over previous
//
#include <hip/hip_runtime.h>
#include <math.h>
#include <stdint.h>

#define BATCH 4096
#define FEAT  1024
#define EDIM  16
#define NDOM  8
#define TDIM  1040   // FEAT + EDIM
#define KP1   1088   // TDIM padded to multiple of 64
#define NLAYER 3
#define EPSV  1e-5f

typedef __attribute__((ext_vector_type(8))) short bf16x8;
typedef __attribute__((ext_vector_type(4))) float f32x4;

__device__ __forceinline__ unsigned short f2bf(float f) {
    union { float f; unsigned int u; } v; v.f = f;
    unsigned int u = v.u;
    return (unsigned short)((u + 0x7fffu + ((u >> 16) & 1u)) >> 16);
}
__device__ __forceinline__ float bf2f(unsigned short u) {
    union { unsigned int u; float f; } v; v.u = ((unsigned int)u) << 16; return v.f;
}
__device__ __forceinline__ void gload_lds16(const void* g, void* l) {
    __builtin_amdgcn_global_load_lds(
        (const __attribute__((address_space(1))) void*)(g),
        (__attribute__((address_space(3))) void*)(l), 16, 0, 0);
}

// 64x64 convert tiles
#define T_W1 136
#define T_W2 32
#define T_W3 8
#define NCONV (T_W1*9 + T_W2*9 + T_W3*9)   // 1584

// ======== kernel 1 "front": converts + grouping + prep (R11-proven) ========
__global__ __launch_bounds__(256) void front(
    const int* __restrict__ dom, int* __restrict__ perm, int* __restrict__ starts,
    const float* __restrict__ cW1, const float* __restrict__ dW1,
    const float* __restrict__ cW2, const float* __restrict__ dW2,
    const float* __restrict__ cW3, const float* __restrict__ dW3,
    unsigned short* __restrict__ Wc1b, unsigned short* __restrict__ Wd1b,
    unsigned short* __restrict__ Wc2b, unsigned short* __restrict__ Wd2b,
    unsigned short* __restrict__ Wc3b, unsigned short* __restrict__ Wd3b,
    const float* __restrict__ x,
    const float* __restrict__ pnw, const float* __restrict__ pnb,
    const float* __restrict__ demb,
    const float* __restrict__ crw, const float* __restrict__ crb,
    const float* __restrict__ aW1, const float* __restrict__ ab1,
    const float* __restrict__ aW2, const float* __restrict__ ab2,
    unsigned short* __restrict__ XCb, float* __restrict__ auxg) {
    int b = blockIdx.x;
    int t = threadIdx.x;

    if (b < NCONV) {
        __shared__ float tile[64][65];
        const float* src; unsigned short* dst; int K, N, Kp, rr;
        if (b < T_W1)            { src = cW1; dst = Wc1b; K = TDIM; N = 512; Kp = KP1; rr = b; }
        else if (b < T_W1*9)     { int r = b - T_W1; int z = r / T_W1; rr = r % T_W1;
                                   src = dW1 + (size_t)z * TDIM * 512; dst = Wd1b + (size_t)z * 512 * KP1;
                                   K = TDIM; N = 512; Kp = KP1; }
        else if (b < T_W1*9+T_W2)   { src = cW2; dst = Wc2b; K = 512; N = 256; Kp = 512; rr = b - T_W1*9; }
        else if (b < T_W1*9+T_W2*9) { int r = b - (T_W1*9+T_W2); int z = r / T_W2; rr = r % T_W2;
                                   src = dW2 + (size_t)z * 512 * 256; dst = Wd2b + (size_t)z * 256 * 512;
                                   K = 512; N = 256; Kp = 512; }
        else if (b < T_W1*9+T_W2*9+T_W3) { src = cW3; dst = Wc3b; K = 256; N = 128; Kp = 256; rr = b - (T_W1*9+T_W2*9); }
        else                     { int r = b - (T_W1*9+T_W2*9+T_W3); int z = r / T_W3; rr = r % T_W3;
                                   src = dW3 + (size_t)z * 256 * 128; dst = Wd3b + (size_t)z * 128 * 256;
                                   K = 256; N = 128; Kp = 256; }
        int kt = Kp >> 6;
        int kb = rr % kt, nb = rr / kt;
        int k0 = kb * 64, n0 = nb * 64;
        #pragma unroll
        for (int i = 0; i < 4; i++) {
            int flat = t + i * 256;
            int kr = flat >> 4, c4 = flat & 15;
            int k = k0 + kr;
            float4 v = make_float4(0.f, 0.f, 0.f, 0.f);
            if (k < K) v = *(const float4*)(src + (size_t)k * N + n0 + c4 * 4);
            tile[kr][c4 * 4 + 0] = v.x;
            tile[kr][c4 * 4 + 1] = v.y;
            tile[kr][c4 * 4 + 2] = v.z;
            tile[kr][c4 * 4 + 3] = v.w;
        }
        __syncthreads();
        #pragma unroll
        for (int i = 0; i < 4; i++) {
            int flat = t + i * 256;
            int n = flat >> 4, kg = flat & 15;
            ushort4 sv;
            sv.x = f2bf(tile[kg * 4 + 0][n]);
            sv.y = f2bf(tile[kg * 4 + 1][n]);
            sv.z = f2bf(tile[kg * 4 + 2][n]);
            sv.w = f2bf(tile[kg * 4 + 3][n]);
            *(ushort4*)(dst + (size_t)(n0 + n) * Kp + k0 + kg * 4) = sv;
        }
        return;
    }
    if (b == NCONV) {
        __shared__ int cnt[NDOM];
        __shared__ int off[NDOM];
        if (t < NDOM) cnt[t] = 0;
        __syncthreads();
        for (int i = t; i < BATCH; i += 256) atomicAdd(&cnt[dom[i]], 1);
        __syncthreads();
        if (t == 0) {
            int s = 0;
            for (int d = 0; d < NDOM; d++) { off[d] = s; starts[d] = s; s += cnt[d]; }
            starts[NDOM] = s;
        }
        __syncthreads();
        for (int i = t; i < BATCH; i += 256) {
            int p = atomicAdd(&off[dom[i]], 1);
            perm[p] = i;
        }
        return;
    }

    // ---- prep: one wave per row, row in registers, barrier-free ----
    int w = t >> 6, lane = t & 63;
    int row = (b - NCONV - 1) * 4 + w;
    int d = dom[row];

    float4 X[4];
    #pragma unroll
    for (int j = 0; j < 4; j++)
        X[j] = *(const float4*)(x + (size_t)row * FEAT + 4 * lane + 256 * j);

    float s = 0.f, ss = 0.f;
    #pragma unroll
    for (int j = 0; j < 4; j++) {
        s  += X[j].x + X[j].y + X[j].z + X[j].w;
        ss += X[j].x*X[j].x + X[j].y*X[j].y + X[j].z*X[j].z + X[j].w*X[j].w;
    }
    #pragma unroll
    for (int m = 1; m < 64; m <<= 1) {
        s  += __shfl_xor(s,  m);
        ss += __shfl_xor(ss, m);
    }
    float mean = s / (float)FEAT;
    float var  = ss / (float)FEAT - mean * mean;
    float rstd = rsqrtf(var + EPSV);

    float4 x0[4], xc[4];
    #pragma unroll
    for (int j = 0; j < 4; j++) {
        float4 wv = *(const float4*)(pnw + (size_t)d * FEAT + 4 * lane + 256 * j);
        float4 bv = *(const float4*)(pnb + (size_t)d * FEAT + 4 * lane + 256 * j);
        x0[j].x = (X[j].x - mean) * rstd * wv.x + bv.x;
        x0[j].y = (X[j].y - mean) * rstd * wv.y + bv.y;
        x0[j].z = (X[j].z - mean) * rstd * wv.z + bv.z;
        x0[j].w = (X[j].w - mean) * rstd * wv.w + bv.w;
        xc[j] = x0[j];
    }
    float x0e = 0.f, xce = 0.f;
    if (lane < EDIM) { x0e = demb[d * EDIM + lane]; xce = x0e; }

    #pragma unroll
    for (int l = 0; l < NLAYER; l++) {
        const float* wl = crw + l * TDIM;
        const float* bl = crb + l * TDIM;
        float partial = 0.f;
        #pragma unroll
        for (int j = 0; j < 4; j++) {
            float4 wv = *(const float4*)(wl + 4 * lane + 256 * j);
            partial += xc[j].x*wv.x + xc[j].y*wv.y + xc[j].z*wv.z + xc[j].w*wv.w;
        }
        if (lane < EDIM) partial += xce * wl[FEAT + lane];
        #pragma unroll
        for (int m = 1; m < 64; m <<= 1) partial += __shfl_xor(partial, m);
        float proj = partial;
        #pragma unroll
        for (int j = 0; j < 4; j++) {
            float4 bv = *(const float4*)(bl + 4 * lane + 256 * j);
            xc[j].x = fmaf(x0[j].x, proj, bv.x + xc[j].x);
            xc[j].y = fmaf(x0[j].y, proj, bv.y + xc[j].y);
            xc[j].z = fmaf(x0[j].z, proj, bv.z + xc[j].z);
            xc[j].w = fmaf(x0[j].w, proj, bv.w + xc[j].w);
        }
        if (lane < EDIM) xce = fmaf(x0e, proj, bl[FEAT + lane] + xce);
    }

    #pragma unroll
    for (int j = 0; j < 4; j++) {
        ushort4 sv;
        sv.x = f2bf(xc[j].x); sv.y = f2bf(xc[j].y);
        sv.z = f2bf(xc[j].z); sv.w = f2bf(xc[j].w);
        *(ushort4*)(XCb + (size_t)row * KP1 + 4 * lane + 256 * j) = sv;
    }
    XCb[(size_t)row * KP1 + FEAT + lane] = (lane < EDIM) ? f2bf(xce) : 0;

    float h = (lane < 32) ? ab1[lane] : 0.f;
    #pragma unroll
    for (int e = 0; e < EDIM; e++) {
        float ev = __shfl(xce, e);
        if (lane < 32) h = fmaf(ev, aW1[e * 32 + lane], h);
    }
    float c = (lane < 32) ? fmaxf(h, 0.f) * aW2[lane] : 0.f;
    #pragma unroll
    for (int m = 1; m < 64; m <<= 1) c += __shfl_xor(c, m);
    if (lane == 0) auxg[row] = c + ab2[0];
}

// ======== L1 GEMM: 128x64 tile, BK=64 (R11-proven) ========
__global__ __launch_bounds__(256) void gemm_mfma_v3(
    const unsigned short* __restrict__ Ac, const unsigned short* __restrict__ Ad, int lda,
    const unsigned short* __restrict__ Wc, const unsigned short* __restrict__ Wd,
    const float* __restrict__ bc, const float* __restrict__ bd,
    unsigned short* __restrict__ Cc, unsigned short* __restrict__ Cd,
    const int* __restrict__ starts, const int* __restrict__ perm, int usePerm,
    int Kp, int N, int relu) {
    __shared__ short As[128 * 64];
    __shared__ short Bs[64 * 64];

    const unsigned short* A; const unsigned short* W; const float* bias;
    unsigned short* C;
    int m0, mEnd;
    int y = blockIdx.y;
    if (y < 32) {
        A = Ac; W = Wc; bias = bc; C = Cc;
        m0 = y * 128; mEnd = BATCH;
    } else {
        int yy = y - 32;
        int d = yy >> 5, sl = yy & 31;
        int ds = starts[d], de = starts[d + 1];
        m0 = ds + sl * 128;
        if (m0 >= de) return;
        mEnd = de;
        A = Ad; W = Wd + (size_t)d * N * Kp; bias = bd + d * N; C = Cd;
    }
    int n0 = blockIdx.x * 64;
    int tid = threadIdx.x;
    int w = tid >> 6, lane = tid & 63;
    int wm = w >> 1, wn = w & 1;
    int lr = lane & 15, q = lane >> 4;

    const unsigned short* pA[4]; const unsigned short* pB[2];
    short* dA[4]; short* dB[2];
    #pragma unroll
    for (int i = 0; i < 4; i++) {
        int seg = i * 4 + w;
        int ch = seg * 64 + lane;
        int loc = ch >> 3, c = ch & 7;
        int mm = m0 + loc; if (mm > mEnd - 1) mm = mEnd - 1;
        int rowp = usePerm ? perm[mm] : mm;
        pA[i] = A + (size_t)rowp * lda + ((c ^ (loc & 7)) << 3);
        dA[i] = As + seg * 512;
    }
    #pragma unroll
    for (int i = 0; i < 2; i++) {
        int seg = i * 4 + w;
        int ch = seg * 64 + lane;
        int loc = ch >> 3, c = ch & 7;
        pB[i] = W + (size_t)(n0 + loc) * Kp + ((c ^ (loc & 7)) << 3);
        dB[i] = Bs + seg * 512;
    }

    f32x4 acc[4][2];
    #pragma unroll
    for (int i = 0; i < 4; i++)
        #pragma unroll
        for (int j = 0; j < 2; j++)
            acc[i][j] = (f32x4){0.f, 0.f, 0.f, 0.f};

    for (int k0 = 0; k0 < Kp; k0 += 64) {
        #pragma unroll
        for (int i = 0; i < 4; i++) gload_lds16(pA[i] + k0, dA[i]);
        #pragma unroll
        for (int i = 0; i < 2; i++) gload_lds16(pB[i] + k0, dB[i]);
        __syncthreads();

        #pragma unroll
        for (int half = 0; half < 2; half++) {
            int c = half * 4 + q;
            bf16x8 af[4], bf[2];
            #pragma unroll
            for (int i = 0; i < 4; i++) {
                int m = wm * 64 + i * 16 + lr;
                af[i] = *(const bf16x8*)(As + m * 64 + ((c ^ (m & 7)) << 3));
            }
            #pragma unroll
            for (int j = 0; j < 2; j++) {
                int n = wn * 32 + j * 16 + lr;
                bf[j] = *(const bf16x8*)(Bs + n * 64 + ((c ^ (n & 7)) << 3));
            }
            #pragma unroll
            for (int i = 0; i < 4; i++)
                #pragma unroll
                for (int j = 0; j < 2; j++)
                    acc[i][j] = __builtin_amdgcn_mfma_f32_16x16x32_bf16(
                        af[i], bf[j], acc[i][j], 0, 0, 0);
        }
        __syncthreads();
    }

    #pragma unroll
    for (int i = 0; i < 4; i++) {
        #pragma unroll
        for (int j = 0; j < 2; j++) {
            int col = n0 + wn * 32 + j * 16 + lr;
            float bvv = bias[col];
            int rowb = m0 + wm * 64 + i * 16 + q * 4;
            #pragma unroll
            for (int r = 0; r < 4; r++) {
                int row = rowb + r;
                if (row >= mEnd) continue;
                float val = acc[i][j][r] + bvv;
                if (relu) val = fmaxf(val, 0.f);
                C[(size_t)row * N + col] = f2bf(val);
            }
        }
    }
}

// ======== L2 GEMM: 64x64 tile, BK=64 — 2x useful blocks vs 128x64 ========
__global__ __launch_bounds__(256) void gemm_mfma_v4(
    const unsigned short* __restrict__ Ac, const unsigned short* __restrict__ Ad, int lda,
    const unsigned short* __restrict__ Wc, const unsigned short* __restrict__ Wd,
    const float* __restrict__ bc, const float* __restrict__ bd,
    unsigned short* __restrict__ Cc, unsigned short* __restrict__ Cd,
    const int* __restrict__ starts,
    int Kp, int N, int relu) {
    __shared__ short As[64 * 64];   // 8KB
    __shared__ short Bs[64 * 64];   // 8KB

    const unsigned short* A; const unsigned short* W; const float* bias;
    unsigned short* C;
    int m0, mEnd;
    int y = blockIdx.y;
    if (y < 64) {
        A = Ac; W = Wc; bias = bc; C = Cc;
        m0 = y * 64; mEnd = BATCH;
    } else {
        int yy = y - 64;
        int d = yy >> 4, sl = yy & 15;
        int ds = starts[d], de = starts[d + 1];
        m0 = ds + sl * 64;
        if (m0 >= de) return;
        mEnd = de;
        A = Ad; W = Wd + (size_t)d * N * Kp; bias = bd + d * N; C = Cd;
    }
    int n0 = blockIdx.x * 64;
    int tid = threadIdx.x;
    int w = tid >> 6, lane = tid & 63;
    int wm = w >> 1, wn = w & 1;
    int lr = lane & 15, q = lane >> 4;

    const unsigned short* pA[2]; const unsigned short* pB[2];
    short* dA[2]; short* dB[2];
    #pragma unroll
    for (int i = 0; i < 2; i++) {
        int seg = i * 4 + w;
        int ch = seg * 64 + lane;
        int loc = ch >> 3, c = ch & 7;
        int mm = m0 + loc; if (mm > mEnd - 1) mm = mEnd - 1;
        pA[i] = A + (size_t)mm * lda + ((c ^ (loc & 7)) << 3);
        dA[i] = As + seg * 512;
        pB[i] = W + (size_t)(n0 + loc) * Kp + ((c ^ (loc & 7)) << 3);
        dB[i] = Bs + seg * 512;
    }

    f32x4 acc[2][2];
    #pragma unroll
    for (int i = 0; i < 2; i++)
        #pragma unroll
        for (int j = 0; j < 2; j++)
            acc[i][j] = (f32x4){0.f, 0.f, 0.f, 0.f};

    for (int k0 = 0; k0 < Kp; k0 += 64) {
        #pragma unroll
        for (int i = 0; i < 2; i++) gload_lds16(pA[i] + k0, dA[i]);
        #pragma unroll
        for (int i = 0; i < 2; i++) gload_lds16(pB[i] + k0, dB[i]);
        __syncthreads();

        #pragma unroll
        for (int half = 0; half < 2; half++) {
            int c = half * 4 + q;
            bf16x8 af[2], bf[2];
            #pragma unroll
            for (int i = 0; i < 2; i++) {
                int m = wm * 32 + i * 16 + lr;
                af[i] = *(const bf16x8*)(As + m * 64 + ((c ^ (m & 7)) << 3));
            }
            #pragma unroll
            for (int j = 0; j < 2; j++) {
                int n = wn * 32 + j * 16 + lr;
                bf[j] = *(const bf16x8*)(Bs + n * 64 + ((c ^ (n & 7)) << 3));
            }
            #pragma unroll
            for (int i = 0; i < 2; i++)
                #pragma unroll
                for (int j = 0; j < 2; j++)
                    acc[i][j] = __builtin_amdgcn_mfma_f32_16x16x32_bf16(
                        af[i], bf[j], acc[i][j], 0, 0, 0);
        }
        __syncthreads();
    }

    #pragma unroll
    for (int i = 0; i < 2; i++) {
        #pragma unroll
        for (int j = 0; j < 2; j++) {
            int col = n0 + wn * 32 + j * 16 + lr;
            float bvv = bias[col];
            int rowb = m0 + wm * 32 + i * 16 + q * 4;
            #pragma unroll
            for (int r = 0; r < 4; r++) {
                int row = rowb + r;
                if (row >= mEnd) continue;
                float val = acc[i][j][r] + bvv;
                if (relu) val = fmaxf(val, 0.f);
                C[(size_t)row * N + col] = f2bf(val);
            }
        }
    }
}

// ======== fused layer-3 (32-row slots, R7-proven): both chains + STAR + final MLP + sigmoid ========
__global__ __launch_bounds__(256) void gemm3_final(
    const unsigned short* __restrict__ Ac, const unsigned short* __restrict__ Ad,
    const unsigned short* __restrict__ Wc, const unsigned short* __restrict__ Wd,
    const float* __restrict__ bc, const float* __restrict__ bd,
    const float* __restrict__ fW1, const float* __restrict__ fb1,
    const float* __restrict__ fW2, const float* __restrict__ fb2,
    const float* __restrict__ auxg, const int* __restrict__ perm,
    const int* __restrict__ starts, float* __restrict__ out) {
    __shared__ __align__(16) char smem[28672];
    short* As    = (short*)smem;             // [32][64]  4KB
    short* Bs    = (short*)(smem + 4096);    // [128][64] 16KB
    short* fused = (short*)(smem + 20480);   // [32][128] 8KB

    int y = blockIdx.x;
    int d = y >> 7, sl = y & 127;
    int ds = starts[d], de = starts[d + 1];
    int m0 = ds + sl * 32;
    if (m0 >= de) return;
    int mEnd = de;

    int tid = threadIdx.x;
    int w = tid >> 6, lane = tid & 63;
    int wm = w >> 1, wn = w & 1;
    int lr = lane & 15, q = lane >> 4;
    const uint4 zero16 = make_uint4(0u, 0u, 0u, 0u);

    for (int chain = 0; chain < 2; chain++) {
        const unsigned short* A = chain ? Ad : Ac;
        const unsigned short* W = chain ? (Wd + (size_t)d * 128 * 256) : Wc;
        const float* bias = chain ? (bd + d * 128) : bc;
        f32x4 acc[4];
        #pragma unroll
        for (int j = 0; j < 4; j++) acc[j] = (f32x4){0.f, 0.f, 0.f, 0.f};

        for (int k0 = 0; k0 < 256; k0 += 64) {
            {   // A: 32 rows x 8 chunks = 256 chunks, 1/thread
                int m = tid >> 3, c = tid & 7;
                int row = m0 + m;
                uint4 val = (row < mEnd)
                    ? *(const uint4*)(A + (size_t)row * 256 + k0 + c * 8) : zero16;
                *(uint4*)(As + m * 64 + ((c ^ (m & 7)) * 8)) = val;
            }
            #pragma unroll
            for (int i = 0; i < 4; i++) {   // B: 128 x 8 = 1024 chunks
                int flat = tid + i * 256;
                int n = flat >> 3, c = flat & 7;
                uint4 val = *(const uint4*)(W + (size_t)n * 256 + k0 + c * 8);
                *(uint4*)(Bs + n * 64 + ((c ^ (n & 7)) * 8)) = val;
            }
            __syncthreads();
            #pragma unroll
            for (int g = 0; g < 2; g++) {
                int c = g * 4 + q;
                int m = wm * 16 + lr;
                bf16x8 af = *(const bf16x8*)(As + m * 64 + ((c ^ (m & 7)) * 8));
                #pragma unroll
                for (int j = 0; j < 4; j++) {
                    int n = wn * 64 + j * 16 + lr;
                    bf16x8 bf = *(const bf16x8*)(Bs + n * 64 + ((c ^ (n & 7)) * 8));
                    acc[j] = __builtin_amdgcn_mfma_f32_16x16x32_bf16(af, bf, acc[j], 0, 0, 0);
                }
            }
            __syncthreads();
        }
        #pragma unroll
        for (int j = 0; j < 4; j++) {
            int col = wn * 64 + j * 16 + lr;
            float bvv = bias[col];
            int cch = col >> 3;
            #pragma unroll
            for (int r = 0; r < 4; r++) {
                int row = wm * 16 + q * 4 + r;
                int pc = (cch & 8) | ((cch ^ (row & 7)) & 7);
                int idx = row * 128 + pc * 8 + (col & 7);
                if (chain == 0) {
                    fused[idx] = (short)f2bf(acc[j][r] + bvv);
                } else {
                    float cv = bf2f((unsigned short)fused[idx]);
                    fused[idx] = (short)f2bf(cv * tanhf(acc[j][r] + bvv));
                }
            }
        }
        __syncthreads();
    }

    // stage fW1 (128k x 64n fp32) -> Bsf[n][k] bf16 swizzled (aliases Bs)
    short* Bsf = Bs;
    float* Ls  = (float*)As;
    for (int s2 = tid; s2 < 1024; s2 += 256) {
        int n = s2 >> 4, cch = s2 & 15;
        bf16x8 vv;
        #pragma unroll
        for (int kk = 0; kk < 8; kk++)
            vv[kk] = (short)f2bf(fW1[(cch * 8 + kk) * 64 + n]);
        int pc = (cch & 8) | ((cch ^ (n & 7)) & 7);
        *(bf16x8*)(Bsf + n * 128 + pc * 8) = vv;
    }
    __syncthreads();

    // final MLP L1 via MFMA: (32 x 128) @ (128 x 64)
    f32x4 acc2[2];
    #pragma unroll
    for (int j = 0; j < 2; j++) acc2[j] = (f32x4){0.f, 0.f, 0.f, 0.f};
    #pragma unroll
    for (int g = 0; g < 4; g++) {
        int c = g * 4 + q;
        int m = wm * 16 + lr;
        int pcm = (c & 8) | ((c ^ (m & 7)) & 7);
        bf16x8 af = *(const bf16x8*)(fused + m * 128 + pcm * 8);
        #pragma unroll
        for (int j = 0; j < 2; j++) {
            int n = wn * 32 + j * 16 + lr;
            int pcn = (c & 8) | ((c ^ (n & 7)) & 7);
            bf16x8 bf = *(const bf16x8*)(Bsf + n * 128 + pcn * 8);
            acc2[j] = __builtin_amdgcn_mfma_f32_16x16x32_bf16(af, bf, acc2[j], 0, 0, 0);
        }
    }

    float w2v[2], b1v[2];
    #pragma unroll
    for (int j = 0; j < 2; j++) {
        int col = wn * 32 + j * 16 + lr;
        w2v[j] = fW2[col];
        b1v[j] = fb1[col];
    }
    float rowv[4];
    #pragma unroll
    for (int r = 0; r < 4; r++) {
        float v = 0.f;
        #pragma unroll
        for (int j = 0; j < 2; j++)
            v += fmaxf(acc2[j][r] + b1v[j], 0.f) * w2v[j];
        v += __shfl_xor(v, 1);
        v += __shfl_xor(v, 2);
        v += __shfl_xor(v, 4);
        v += __shfl_xor(v, 8);
        rowv[r] = v;
    }
    if (wn == 0 && lr == 0) {
        #pragma unroll
        for (int r = 0; r < 4; r++)
            Ls[wm * 16 + q * 4 + r] = rowv[r];
    }
    __syncthreads();
    if (wn == 1 && lr == 0) {
        float b2 = fb2[0];
        #pragma unroll
        for (int r = 0; r < 4; r++) {
            int row = wm * 16 + q * 4 + r;
            int p = m0 + row;
            if (p < mEnd) {
                int orow = perm[p];
                float logit = Ls[row] + rowv[r] + b2 + auxg[orow];
                out[orow] = 1.f / (1.f + expf(-logit));
            }
        }
    }
}

extern "C" void kernel_launch(void* const* d_in, const int* in_sizes, int n_in,
                              void* d_out, int out_size, void* d_ws, size_t ws_size,
                              hipStream_t stream) {
    (void)in_sizes; (void)n_in; (void)out_size; (void)ws_size;

    const float* x    = (const float*)d_in[0];
    const int*   dom  = (const int*)  d_in[1];
    const float* pnw  = (const float*)d_in[2];
    const float* pnb  = (const float*)d_in[3];
    const float* demb = (const float*)d_in[4];
    const float* crw  = (const float*)d_in[5];
    const float* crb  = (const float*)d_in[6];
    const float* cW1  = (const float*)d_in[7];
    const float* cb1  = (const float*)d_in[8];
    const float* cW2  = (const float*)d_in[9];
    const float* cb2  = (const float*)d_in[10];
    const float* cW3  = (const float*)d_in[11];
    const float* cb3  = (const float*)d_in[12];
    const float* dW1  = (const float*)d_in[13];
    const float* db1  = (const float*)d_in[14];
    const float* dW2  = (const float*)d_in[15];
    const float* db2  = (const float*)d_in[16];
    const float* dW3  = (const float*)d_in[17];
    const float* db3  = (const float*)d_in[18];
    const float* fW1  = (const float*)d_in[19];
    const float* fb1  = (const float*)d_in[20];
    const float* fW2  = (const float*)d_in[21];
    const float* fb2  = (const float*)d_in[22];
    const float* aW1  = (const float*)d_in[23];
    const float* ab1  = (const float*)d_in[24];
    const float* aW2  = (const float*)d_in[25];
    const float* ab2  = (const float*)d_in[26];
    float* out = (float*)d_out;

    char* base = (char*)d_ws;
    size_t o = 0;
    auto alloc = [&](size_t bytes) { char* p = base + o; o += (bytes + 255) & ~size_t(255); return p; };

    int* perm   = (int*)alloc(BATCH * 4);
    int* starts = (int*)alloc((NDOM + 1) * 4);
    float* auxg = (float*)alloc(BATCH * 4);
    unsigned short* XCb  = (unsigned short*)alloc((size_t)BATCH * KP1 * 2);
    unsigned short* H1c  = (unsigned short*)alloc((size_t)BATCH * 512 * 2);
    unsigned short* H1d  = (unsigned short*)alloc((size_t)BATCH * 512 * 2);
    unsigned short* H2c  = (unsigned short*)alloc((size_t)BATCH * 256 * 2);
    unsigned short* H2d  = (unsigned short*)alloc((size_t)BATCH * 256 * 2);
    unsigned short* Wc1b = (unsigned short*)alloc((size_t)512 * KP1 * 2);
    unsigned short* Wd1b = (unsigned short*)alloc((size_t)NDOM * 512 * KP1 * 2);
    unsigned short* Wc2b = (unsigned short*)alloc((size_t)256 * 512 * 2);
    unsigned short* Wd2b = (unsigned short*)alloc((size_t)NDOM * 256 * 512 * 2);
    unsigned short* Wc3b = (unsigned short*)alloc((size_t)128 * 256 * 2);
    unsigned short* Wd3b = (unsigned short*)alloc((size_t)NDOM * 128 * 256 * 2);

    // 1) convert + grouping + prep (one launch)
    front<<<NCONV + 1 + BATCH / 4, 256, 0, stream>>>(
        dom, perm, starts, cW1, dW1, cW2, dW2, cW3, dW3,
        Wc1b, Wd1b, Wc2b, Wd2b, Wc3b, Wd3b,
        x, pnw, pnb, demb, crw, crb, aW1, ab1, aW2, ab2, XCb, auxg);

    // 2) L1: (4096 x 1088) -> 512, relu (A gathered via perm), 128x64 tiles
    gemm_mfma_v3<<<dim3(512 / 64, 32 + NDOM * 32), 256, 0, stream>>>(
        XCb, XCb, KP1, Wc1b, Wd1b, cb1, db1, H1c, H1d, starts, perm, 1, KP1, 512, 1);
    // 3) L2: (4096 x 512) -> 256, relu, 64x64 tiles (more blocks)
    gemm_mfma_v4<<<dim3(256 / 64, 64 + NDOM * 16), 256, 0, stream>>>(
        H1c, H1d, 512, Wc2b, Wd2b, cb2, db2, H2c, H2d, starts, 512, 256, 1);

    // 4) L3 + STAR + final MLP + sigmoid (32-row slots, 128 useful blocks)
    gemm3_final<<<NDOM * 128, 256, 0, stream>>>(
        H2c, H2d, Wc3b, Wd3b, cb3, db3, fW1, fb1, fW2, fb2,
        auxg, perm, starts, out);
}